// Round 15
// baseline (457.148 us; speedup 1.0000x reference)
//
#include <hip/hip_runtime.h>
#include <math.h>

#define NB   16
#define SS   256
#define DIMV 41
#define NDV  42
#define NKD  128
#define NHD  4
#define DH   32
#define NLAY 3
#define TOT  (SS*NDV)   // 10752 = 42 chunks of 256
#define NCH  42

typedef __attribute__((ext_vector_type(8))) short short8;
typedef __attribute__((ext_vector_type(4))) float floatx4;

__device__ __forceinline__ short f2bf(float x) {
    unsigned u = __float_as_uint(x);
    u += 0x7fff + ((u >> 16) & 1);          // RNE f32 -> bf16
    return (short)(u >> 16);
}
__device__ __forceinline__ float bfs2f(short s) {
    return __uint_as_float(((unsigned)(unsigned short)s) << 16);
}
__device__ __forceinline__ float bf2f(unsigned s) {
    return __uint_as_float(s << 16);
}

struct Seg { const short* ptr; const int* ind; int ns; };

__device__ __forceinline__ const short* seg_row(const Seg s, int gm, int Lb) {
    if (s.ind) {
        int b = gm / Lb;
        int id = s.ind[gm]; if (id < 0) id = 0;
        return s.ptr + ((size_t)b * s.ns + (size_t)id) * NKD;
    }
    return s.ptr + (size_t)gm * NKD;
}

// ===========================================================================
// Device bodies
// ===========================================================================

__device__ __forceinline__ void zero_body(int bx, int* __restrict__ lo_t,
                                          int* __restrict__ hi_t)
{
    int i = bx*256 + threadIdx.x;
    if (i < NB*SS) { lo_t[i] = 0; hi_t[i] = 0; }
}

__device__ __forceinline__ void initT_body(int bx, const float* __restrict__ cx,
                                           const float* __restrict__ tw,
                                           const float* __restrict__ tb,
                                           short* __restrict__ T)
{
    int i = bx * 256 + threadIdx.x;
    if (i >= NB*SS*16) return;
    int row = i >> 4;
    int k = (i & 15) << 3;
    float t = cx[row];
    short8 r;
    #pragma unroll
    for (int j = 0; j < 8; j++) r[j] = f2bf(sinf(t*tw[k+j] + tb[k+j]));
    *(short8*)(T + (size_t)row*NKD + k) = r;
}

__device__ __forceinline__ void initC_body(int bx, const float* __restrict__ cw,
                                           const float* __restrict__ cb,
                                           short* __restrict__ C)
{
    int i = bx * 256 + threadIdx.x;
    if (i >= NB*NDV*16) return;
    int row = i >> 4;
    int c = row % NDV;
    int k = (i & 15) << 3;
    short8 r;
    #pragma unroll
    for (int j = 0; j < 8; j++) r[j] = f2bf(fmaxf(cw[(size_t)c*NKD + k+j] + cb[k+j], 0.f));
    *(short8*)(C + (size_t)row*NKD + k) = r;
}

template<int Kg>
__device__ __forceinline__ void prep1(const float* __restrict__ src,
                                      short* __restrict__ dst, int rel)
{
    const int per = Kg*128;
    int i = rel / per; int r2 = rel - i*per;
    int n = r2 / Kg;   int k = r2 - n*Kg;
    dst[rel] = f2bf(src[(size_t)i*per + (size_t)k*128 + n]);
}

#define W_TOTAL 933888
__device__ __forceinline__ void prepw_body(int bx,
    const float* ctq, const float* ctk, const float* ctv, const float* cto,
    const float* tcq, const float* tck, const float* tcv, const float* tco,
    const float* caq, const float* cak, const float* cav, const float* cao,
    const float* enw, short* __restrict__ arena)
{
    int idx = bx*256 + threadIdx.x;
    if (idx >= W_TOTAL) return;
    if      (idx < 49152 ) prep1<128>(ctq, arena + 0,      idx - 0);
    else if (idx < 147456) prep1<256>(ctk, arena + 49152,  idx - 49152);
    else if (idx < 245760) prep1<256>(ctv, arena + 147456, idx - 147456);
    else if (idx < 294912) prep1<128>(cto, arena + 245760, idx - 245760);
    else if (idx < 344064) prep1<128>(tcq, arena + 294912, idx - 294912);
    else if (idx < 442368) prep1<256>(tck, arena + 344064, idx - 344064);
    else if (idx < 540672) prep1<256>(tcv, arena + 442368, idx - 442368);
    else if (idx < 589824) prep1<128>(tco, arena + 540672, idx - 540672);
    else if (idx < 638976) prep1<128>(caq, arena + 589824, idx - 589824);
    else if (idx < 688128) prep1<128>(cak, arena + 638976, idx - 638976);
    else if (idx < 737280) prep1<128>(cav, arena + 688128, idx - 688128);
    else if (idx < 786432) prep1<128>(cao, arena + 737280, idx - 737280);
    else                   prep1<384>(enw, arena + 786432, idx - 786432);
}

// compactC with in-block chunk counting (compactA + compactB folded in):
// block (b,ch): all 4 waves count every chunk of batch b (wave-strided),
// wave 0 scans the 42 counts, then stable scatter as before.
__device__ __forceinline__ void compactC_body(int blk,
              const float* __restrict__ cx, const float* __restrict__ value,
              const float* __restrict__ maskp, const float* __restrict__ tval,
              const float* __restrict__ tmaskp, const float* __restrict__ w0p,
              const float* __restrict__ b0p, int L,
              int* __restrict__ tind, int* __restrict__ cind,
              float* __restrict__ mkb, float* __restrict__ uval,
              float* __restrict__ uind,
              float* __restrict__ outTU, float* __restrict__ outTM)
{
    const int b = blk / NCH, ch = blk % NCH;
    const int tid = threadIdx.x, lane = tid & 63, wv = tid >> 6;
    __shared__ int cc[NCH];
    __shared__ int wsum[4];
    __shared__ int s_off, s_cnt;

    // own-element mask + wave scan (for the scatter)
    const int idx = ch * 256 + tid;
    const int s = idx / NDV, c = idx % NDV;
    float mval = (c < DIMV) ? maskp[((size_t)b*SS + s)*DIMV + c] : 1.0f;
    int m = (mval != 0.0f) ? 1 : 0;
    int x = m;
    #pragma unroll
    for (int off = 1; off < 64; off <<= 1) {
        int y = __shfl_up(x, off);
        if (lane >= off) x += y;
    }
    if (lane == 63) wsum[wv] = x;

    // per-chunk counts: wave w handles chunks w, w+4, ...
    for (int j = wv; j < NCH; j += 4) {
        int cnt = 0;
        #pragma unroll
        for (int i = 0; i < 4; i++) {
            int idx2 = j*256 + lane + 64*i;
            int s2 = idx2 / NDV, c2 = idx2 % NDV;
            float m2 = (c2 < DIMV) ? maskp[((size_t)b*SS + s2)*DIMV + c2] : 1.0f;
            cnt += (m2 != 0.0f) ? 1 : 0;
        }
        #pragma unroll
        for (int off = 32; off; off >>= 1) cnt += __shfl_down(cnt, off);
        if (lane == 0) cc[j] = cnt;
    }
    __syncthreads();
    // wave 0: exclusive scan of 42 counts
    if (tid < 64) {
        int v2 = (tid < NCH) ? cc[tid] : 0;
        int x2 = v2;
        #pragma unroll
        for (int off = 1; off < 64; off <<= 1) {
            int y2 = __shfl_up(x2, off);
            if (tid >= off) x2 += y2;
        }
        if (tid == ch) s_off = x2 - v2;
        if (tid == 63) s_cnt = x2;
    }
    __syncthreads();
    int wbase = 0;
    for (int w = 0; w < wv; w++) wbase += wsum[w];
    const int excl = x - m + wbase;
    const int vbefore = s_off + excl;
    const int cnt = s_cnt;
    const int pos = m ? vbefore : (cnt + (idx - vbefore));
    if (pos < L) {
        const float w0 = w0p[0], b0 = b0p[0];
        float te = w0 * cx[(size_t)b*SS + s] + b0;
        float vf, tvf, tmf;
        if (c < DIMV) {
            size_t o = ((size_t)b*SS + s)*DIMV + c;
            vf = value[o]; tvf = tval[o]; tmf = tmaskp[o];
        } else { vf = te; tvf = te; tmf = 0.0f; }
        size_t p = (size_t)b*L + pos;
        if (m) {
            tind[p] = s; cind[p] = c; mkb[p] = 1.0f;
            uval[p] = vf; uind[p] = tmf;
            outTU[p] = tvf; outTM[p] = tmf;
        } else {
            tind[p] = -1; cind[p] = -1; mkb[p] = 0.0f;
            uval[p] = 0.0f; uind[p] = 1.0f;
            outTU[p] = 0.0f; outTM[p] = 0.0f;
        }
    }
}

__device__ __forceinline__ void trange_body(int bx, const int* __restrict__ tind,
                                            int* __restrict__ lo_t,
                                            int* __restrict__ hi_t, int L)
{
    int p = bx*256 + threadIdx.x;
    if (p >= NB*L) return;
    int b = p / L, l = p - b*L;
    int t = tind[p];
    if (t < 0) return;
    int tp = (l > 0) ? tind[p-1] : -999;
    int tn = (l+1 < L) ? tind[p+1] : -999;
    if (tp != t) lo_t[b*SS + t] = l;
    if (tn != t) hi_t[b*SS + t] = l+1;
}

__device__ __forceinline__ void cperm_body(int b, const int* __restrict__ cind,
                                           int* __restrict__ invp,
                                           int* __restrict__ clo,
                                           int* __restrict__ chi, int L)
{
    __shared__ int hist[NDV];
    __shared__ int base[NDV];
    __shared__ int padc, cntsh;
    const int tid = threadIdx.x;
    if (tid < NDV) hist[tid] = 0;
    if (tid == 0) padc = 0;
    __syncthreads();
    for (int l = tid; l < L; l += 256) {
        int c = cind[(size_t)b*L + l];
        if (c >= 0) atomicAdd(&hist[c], 1);
    }
    __syncthreads();
    if (tid == 0) {
        int run = 0;
        for (int c = 0; c < NDV; c++) {
            base[c] = run; clo[b*NDV + c] = run;
            run += hist[c]; chi[b*NDV + c] = run;
        }
        cntsh = run;
    }
    __syncthreads();
    if (tid < NDV) hist[tid] = 0;
    __syncthreads();
    const int cnt = cntsh;
    for (int l = tid; l < L; l += 256) {
        int c = cind[(size_t)b*L + l];
        int pos;
        if (c >= 0) pos = base[c] + atomicAdd(&hist[c], 1);
        else        pos = cnt + atomicAdd(&padc, 1);
        invp[(size_t)b*L + l] = b*L + pos;
    }
}

__device__ __forceinline__ void initU_body(int bx, const float* __restrict__ uval,
                                           const float* __restrict__ uind,
                                           const float* __restrict__ mkb,
                                           const float* __restrict__ ew,
                                           const float* __restrict__ eb,
                                           short* __restrict__ U, int BL)
{
    int i = bx * 256 + threadIdx.x;
    if (i >= BL*16) return;
    int row = i >> 4;
    int k = (i & 15) << 3;
    float uv = uval[row], ui = uind[row], m = mkb[row];
    short8 r;
    #pragma unroll
    for (int j = 0; j < 8; j++)
        r[j] = f2bf(fmaxf(uv*ew[k+j] + ui*ew[NKD+k+j] + eb[k+j], 0.f) * m);
    *(short8*)(U + (size_t)row*NKD + k) = r;
}

// ---------------------------------------------------------------------------
// MFMA GEMM body (M-tile 128), bf16 activations in/out. smem >= 20480
// MODE 0: D = acc+b ; MODE 2: D = A0 + relu(acc+b) ; MODE 3: relu(A0+acc+b)*mk
// ---------------------------------------------------------------------------
template<int NSEG, int MODE>
__device__ __forceinline__ void mgemm_body(char* smem, int bx,
           Seg s0, Seg s1, Seg s2, const short* __restrict__ Wt,
           const float* __restrict__ bias, short* __restrict__ D,
           int M, int Lb, const float* __restrict__ mkp)
{
    short (*As)[40] = (short (*)[40])smem;
    short (*Bs)[40] = (short (*)[40])(smem + 10240);
    const int bm = bx * 128;
    const int tid = threadIdx.x;
    const int wv = tid >> 6;
    const int lane = tid & 63;
    const int quad = lane >> 4;
    const int l16 = lane & 15;
    const int K = NSEG * 128;
    floatx4 acc[2][8];
    #pragma unroll
    for (int i = 0; i < 2; i++)
        #pragma unroll
        for (int j = 0; j < 8; j++) acc[i][j] = (floatx4){0.f,0.f,0.f,0.f};

    const int arow = tid >> 1;
    const int acol = (tid & 1) * 16;
    int gmc = bm + arow; if (gmc > M-1) gmc = M-1;
    const short* rowp0 = seg_row(s0, gmc, Lb);
    const short* rowp1 = (NSEG > 1) ? seg_row(s1, gmc, Lb) : nullptr;
    const short* rowp2 = (NSEG > 2) ? seg_row(s2, gmc, Lb) : nullptr;

    for (int k0 = 0; k0 < K; k0 += 32) {
        {
            const short* rp;
            if (NSEG == 1) rp = rowp0;
            else if (NSEG == 2) rp = (k0 < 128) ? rowp0 : rowp1;
            else rp = (k0 < 128) ? rowp0 : ((k0 < 256) ? rowp1 : rowp2);
            const int ks = k0 & 127;
            const short* src = rp + ks + acol;
            *(short8*)&As[arow][acol]   = *(const short8*)(src);
            *(short8*)&As[arow][acol+8] = *(const short8*)(src+8);
        }
        {
            const short* src = Wt + (size_t)arow*K + k0 + acol;
            *(short8*)&Bs[arow][acol]   = *(const short8*)(src);
            *(short8*)&Bs[arow][acol+8] = *(const short8*)(src+8);
        }
        __syncthreads();
        short8 af0 = *(short8*)&As[wv*32 + l16][quad*8];
        short8 af1 = *(short8*)&As[wv*32 + 16 + l16][quad*8];
        #pragma unroll
        for (int nf = 0; nf < 8; nf++) {
            short8 bf = *(short8*)&Bs[nf*16 + l16][quad*8];
            acc[0][nf] = __builtin_amdgcn_mfma_f32_16x16x32_bf16(af0, bf, acc[0][nf], 0, 0, 0);
            acc[1][nf] = __builtin_amdgcn_mfma_f32_16x16x32_bf16(af1, bf, acc[1][nf], 0, 0, 0);
        }
        __syncthreads();
    }
    #pragma unroll
    for (int mf = 0; mf < 2; mf++) {
        #pragma unroll
        for (int r = 0; r < 4; r++) {
            int gm = bm + wv*32 + mf*16 + quad*4 + r;
            if (gm < M) {
                float mk = (MODE == 3) ? mkp[gm] : 0.f;
                const short* res = (MODE == 2 || MODE == 3) ? seg_row(s0, gm, Lb) : nullptr;
                #pragma unroll
                for (int nf = 0; nf < 8; nf++) {
                    int gn = nf*16 + l16;
                    float val = acc[mf][nf][r] + bias[gn];
                    if (MODE == 2) val = bfs2f(res[gn]) + fmaxf(val, 0.f);
                    else if (MODE == 3) val = fmaxf(bfs2f(res[gn]) + val, 0.f) * mk;
                    D[(size_t)gm*NKD + gn] = f2bf(val);
                }
            }
        }
    }
}

// ---------------------------------------------------------------------------
// Dual-output KV GEMM body, M-tile 32 (better occupancy for P1):
// 4 waves = 2 row-frags x 2 n-halves. packed bf16 (k | v<<16). smem >= 23040
// ---------------------------------------------------------------------------
template<int NSEG>
__device__ __forceinline__ void mgemm_kv32_body(char* smem, int bx,
              Seg s0, Seg s1,
              const short* __restrict__ Wk, const float* __restrict__ bk,
              const short* __restrict__ Wv, const float* __restrict__ bv,
              unsigned* __restrict__ KV, int M, int Lb, const int* __restrict__ rmap)
{
    short (*As)[40]  = (short (*)[40])smem;              // 32 rows: 2560 B
    short (*Bk_)[40] = (short (*)[40])(smem + 2560);
    short (*Bv_)[40] = (short (*)[40])(smem + 12800);
    const int bm = bx * 32;
    const int tid = threadIdx.x;
    const int wv = tid >> 6;
    const int lane = tid & 63;
    const int quad = lane >> 4;
    const int l16 = lane & 15;
    const int mf = wv >> 1;        // row-frag (0/1)
    const int nh = wv & 1;         // n-half (0/1)
    const int K = NSEG * 128;
    floatx4 acck[4], accv[4];
    #pragma unroll
    for (int j = 0; j < 4; j++) {
        acck[j] = (floatx4){0.f,0.f,0.f,0.f};
        accv[j] = (floatx4){0.f,0.f,0.f,0.f};
    }

    const int arow = (tid & 127) >> 2;    // 0..31 (only tid<128 stores)
    const int acol = (tid & 3) * 8;
    const int brow = tid >> 1;
    const int bcol = (tid & 1) * 16;
    int gmc = bm + arow; if (gmc > M-1) gmc = M-1;
    const short* rowp0 = seg_row(s0, gmc, Lb);
    const short* rowp1 = (NSEG > 1) ? seg_row(s1, gmc, Lb) : nullptr;

    for (int k0 = 0; k0 < K; k0 += 32) {
        if (tid < 128) {
            const short* rp = (NSEG == 1) ? rowp0 : ((k0 < 128) ? rowp0 : rowp1);
            const int ks = k0 & 127;
            *(short8*)&As[arow][acol] = *(const short8*)(rp + ks + acol);
        }
        {
            const short* sk = Wk + (size_t)brow*K + k0 + bcol;
            *(short8*)&Bk_[brow][bcol]   = *(const short8*)(sk);
            *(short8*)&Bk_[brow][bcol+8] = *(const short8*)(sk+8);
            const short* sv = Wv + (size_t)brow*K + k0 + bcol;
            *(short8*)&Bv_[brow][bcol]   = *(const short8*)(sv);
            *(short8*)&Bv_[brow][bcol+8] = *(const short8*)(sv+8);
        }
        __syncthreads();
        short8 af = *(short8*)&As[mf*16 + l16][quad*8];
        #pragma unroll
        for (int nf = 0; nf < 4; nf++) {
            short8 bfk = *(short8*)&Bk_[nh*64 + nf*16 + l16][quad*8];
            acck[nf] = __builtin_amdgcn_mfma_f32_16x16x32_bf16(af, bfk, acck[nf], 0, 0, 0);
            short8 bfv = *(short8*)&Bv_[nh*64 + nf*16 + l16][quad*8];
            accv[nf] = __builtin_amdgcn_mfma_f32_16x16x32_bf16(af, bfv, accv[nf], 0, 0, 0);
        }
        __syncthreads();
    }
    #pragma unroll
    for (int r = 0; r < 4; r++) {
        int gm = bm + mf*16 + quad*4 + r;
        if (gm < M) {
            int orow = rmap ? rmap[gm] : gm;
            #pragma unroll
            for (int nf = 0; nf < 4; nf++) {
                int gn = nh*64 + nf*16 + l16;
                float kf = acck[nf][r] + bk[gn];
                float vf = accv[nf][r] + bv[gn];
                unsigned pk = (unsigned)(unsigned short)f2bf(kf)
                            | ((unsigned)(unsigned short)f2bf(vf) << 16);
                KV[(size_t)orow*NKD + gn] = pk;
            }
        }
    }
}

// ---------------------------------------------------------------------------
// Fused ct-o-proj + ca q/k/v (M-tile 64): C2 = oC + relu(oC@wo+bo) lives only
// in LDS; q -> qC (bf16), k/v -> packed kvCa. smem >= 32768.
// ---------------------------------------------------------------------------
__device__ __forceinline__ void octca_body(char* smem, int bx,
    const short* __restrict__ oC,
    const short* __restrict__ wo, const float* __restrict__ bo,
    const short* __restrict__ wq, const float* __restrict__ bq,
    const short* __restrict__ wk, const float* __restrict__ bk,
    const short* __restrict__ wv, const float* __restrict__ bv,
    short* __restrict__ qC, unsigned* __restrict__ KV, int M)
{
    short (*C2t)[136] = (short (*)[136])smem;            // 17408 B
    short (*Bs)[40]   = (short (*)[40])(smem + 17408);   // 10240 B
    short (*As)[40]   = (short (*)[40])(smem + 27648);   // 5120 B
    const int bm = bx * 64;
    const int tid = threadIdx.x;
    const int wv_ = tid >> 6;
    const int lane = tid & 63;
    const int quad = lane >> 4;
    const int l16 = lane & 15;
    const int arow = tid >> 2;
    const int acol = (tid & 3) * 8;
    const int brow = tid >> 1;
    const int bcol = (tid & 1) * 16;
    int gmc = bm + arow; if (gmc > M-1) gmc = M-1;
    const short* rowp = oC + (size_t)gmc * NKD;

    floatx4 acc[8];
    #pragma unroll
    for (int j = 0; j < 8; j++) acc[j] = (floatx4){0.f,0.f,0.f,0.f};
    for (int k0 = 0; k0 < 128; k0 += 32) {
        *(short8*)&As[arow][acol] = *(const short8*)(rowp + k0 + acol);
        const short* sw = wo + (size_t)brow*128 + k0 + bcol;
        *(short8*)&Bs[brow][bcol]   = *(const short8*)(sw);
        *(short8*)&Bs[brow][bcol+8] = *(const short8*)(sw+8);
        __syncthreads();
        short8 af = *(short8*)&As[wv_*16 + l16][quad*8];
        #pragma unroll
        for (int nf = 0; nf < 8; nf++) {
            short8 bf = *(short8*)&Bs[nf*16 + l16][quad*8];
            acc[nf] = __builtin_amdgcn_mfma_f32_16x16x32_bf16(af, bf, acc[nf], 0, 0, 0);
        }
        __syncthreads();
    }
    #pragma unroll
    for (int r = 0; r < 4; r++) {
        int lrow = wv_*16 + quad*4 + r;
        int gm = bm + lrow; int gmr = (gm > M-1) ? (M-1) : gm;
        const short* res = oC + (size_t)gmr*NKD;
        #pragma unroll
        for (int nf = 0; nf < 8; nf++) {
            int gn = nf*16 + l16;
            float val = acc[nf][r] + bo[gn];
            val = bfs2f(res[gn]) + fmaxf(val, 0.f);
            C2t[lrow][gn] = f2bf(val);
        }
    }
    __syncthreads();

    floatx4 acck[8];
    for (int proj = 0; proj < 3; proj++) {
        const short* W = (proj == 0) ? wq : ((proj == 1) ? wk : wv);
        floatx4 a2[8];
        #pragma unroll
        for (int j = 0; j < 8; j++) a2[j] = (floatx4){0.f,0.f,0.f,0.f};
        for (int k0 = 0; k0 < 128; k0 += 32) {
            const short* sw = W + (size_t)brow*128 + k0 + bcol;
            *(short8*)&Bs[brow][bcol]   = *(const short8*)(sw);
            *(short8*)&Bs[brow][bcol+8] = *(const short8*)(sw+8);
            __syncthreads();
            short8 af = *(short8*)&C2t[wv_*16 + l16][k0 + quad*8];
            #pragma unroll
            for (int nf = 0; nf < 8; nf++) {
                short8 bf = *(short8*)&Bs[nf*16 + l16][quad*8];
                a2[nf] = __builtin_amdgcn_mfma_f32_16x16x32_bf16(af, bf, a2[nf], 0, 0, 0);
            }
            __syncthreads();
        }
        if (proj == 0) {
            #pragma unroll
            for (int r = 0; r < 4; r++) {
                int gm = bm + wv_*16 + quad*4 + r;
                if (gm < M) {
                    #pragma unroll
                    for (int nf = 0; nf < 8; nf++) {
                        int gn = nf*16 + l16;
                        qC[(size_t)gm*NKD + gn] = f2bf(a2[nf][r] + bq[gn]);
                    }
                }
            }
        } else if (proj == 1) {
            #pragma unroll
            for (int j = 0; j < 8; j++) acck[j] = a2[j];
        } else {
            #pragma unroll
            for (int r = 0; r < 4; r++) {
                int gm = bm + wv_*16 + quad*4 + r;
                if (gm < M) {
                    #pragma unroll
                    for (int nf = 0; nf < 8; nf++) {
                        int gn = nf*16 + l16;
                        float kf = acck[nf][r] + bk[gn];
                        float vf = a2[nf][r] + bv[gn];
                        KV[(size_t)gm*NKD + gn] =
                            (unsigned)(unsigned short)f2bf(kf)
                          | ((unsigned)(unsigned short)f2bf(vf) << 16);
                    }
                }
            }
        }
    }
}

// ---------------------------------------------------------------------------
// Segmented attention body on packed bf16 KV, bf16 q/o. SPLIT waves/(b,q,h).
// ---------------------------------------------------------------------------
template<int SPLIT>
__device__ __forceinline__ void sattn_body(int bx,
                  const short* __restrict__ q, const unsigned* __restrict__ kvb,
                  short* __restrict__ o, int nq, int nkv,
                  const int* __restrict__ lo_arr, const int* __restrict__ hi_arr)
{
    __shared__ float sm_m[4], sm_s[4], sm_a[4][DH];
    const int wvid = threadIdx.x >> 6;
    int gtask = bx * 4 + wvid;
    int task = gtask / SPLIT;
    int part = gtask % SPLIT;
    if (task >= NB * nq * NHD) return;
    const int h = task & 3;
    const int bq = task >> 2;
    const int qi = bq % nq;
    const int b = bq / nq;
    const int lane = threadIdx.x & 63;
    const int d = lane & 31;
    const int half = lane >> 5;
    int lo = lo_arr ? lo_arr[b*nq + qi] : 0;
    int hi = hi_arr ? hi_arr[b*nq + qi] : nkv;
    if (SPLIT == 2) {
        int mid = lo + ((hi - lo + 1) >> 1);
        if (part == 0) hi = mid; else lo = mid;
    }
    const float scale = 0.088388347648318447f;   // 1/sqrt(128)

    const float qv = bfs2f(q[((size_t)(b*nq + qi))*NKD + h*DH + d]);
    const unsigned* kb = kvb + (size_t)b*nkv*NKD + h*DH + d;

    float m = -INFINITY, ssum = 0.f, acc = 0.f;
    for (int l0 = lo; l0 < hi; l0 += 8) {
        unsigned ur[4];
        #pragma unroll
        for (int j = 0; j < 4; j++) {
            int l = l0 + 2*j + half;
            bool ok = (l < hi);
            ur[j] = ok ? kb[(size_t)l*NKD] : 0u;
        }
        #pragma unroll
        for (int j = 0; j < 4; j++) {
            int l = l0 + 2*j + half;
            float kr = bf2f(ur[j] & 0xffffu);
            float vr = bf2f(ur[j] >> 16);
            float partial = qv * kr;
            #pragma unroll
            for (int off = 16; off; off >>= 1) partial += __shfl_xor(partial, off);
            float s = partial * scale;
            if (l < hi) {
                float mn = fmaxf(m, s);
                float corr = __expf(m - mn);
                float p = __expf(s - mn);
                ssum = ssum * corr + p;
                acc  = acc  * corr + p * vr;
                m = mn;
            }
        }
    }
    float mo = __shfl_xor(m, 32);
    float M = fmaxf(m, mo);
    float corr = (m > -1e30f) ? __expf(m - M) : 0.f;
    ssum *= corr; acc *= corr;
    ssum += __shfl_xor(ssum, 32);
    acc  += __shfl_xor(acc, 32);

    if (SPLIT == 1) {
        if (half == 0) {
            float res = (ssum > 0.f) ? acc / ssum : 0.f;
            o[((size_t)(b*nq + qi))*NKD + h*DH + d] = f2bf(qv + res);
        }
    } else {
        if (lane == 0) { sm_m[wvid] = M; sm_s[wvid] = ssum; }
        if (lane < DH) sm_a[wvid][lane] = acc;
        __syncthreads();
        if (part == 0 && lane < DH) {
            float m2 = sm_m[wvid+1], s2 = sm_s[wvid+1], a2 = sm_a[wvid+1][lane];
            float M2 = fmaxf(M, m2);
            float c1 = (M  > -1e30f) ? __expf(M  - M2) : 0.f;
            float c2 = (m2 > -1e30f) ? __expf(m2 - M2) : 0.f;
            float S = ssum * c1 + s2 * c2;
            float A = acc  * c1 + a2 * c2;
            float res = (S > 0.f) ? A / S : 0.f;
            float qv2 = bfs2f(q[((size_t)(b*nq + qi))*NKD + h*DH + lane]);
            o[((size_t)(b*nq + qi))*NKD + h*DH + lane] = f2bf(qv2 + res);
        }
    }
}

// ===========================================================================
// Kernels
// ===========================================================================

// Pre-phase 1 (everything independent): compactC-self + zero + initT + initC + prepw
__global__ __launch_bounds__(256)
void k_pre_all(const float* cx, const float* value, const float* maskp,
               const float* tval, const float* tmaskp, const float* w0p,
               const float* b0p, int L,
               int* tind, int* cind, float* mkb, float* uval, float* uind,
               float* outTU, float* outTM,
               int* lo_t, int* hi_t,
               const float* tw, const float* tb, short* T,
               const float* cw, const float* cb, short* C,
               const float* ctq, const float* ctk, const float* ctv, const float* cto,
               const float* tcq, const float* tck, const float* tcv, const float* tco,
               const float* caq, const float* cak, const float* cav, const float* cao,
               const float* enw, short* arena)
{
    int bx = blockIdx.x;
    if (bx < NB*NCH)
        compactC_body(bx, cx, value, maskp, tval, tmaskp, w0p, b0p, L,
                      tind, cind, mkb, uval, uind, outTU, outTM);
    else if (bx < NB*NCH + 16)  zero_body(bx - NB*NCH, lo_t, hi_t);
    else if (bx < NB*NCH + 16 + 256) initT_body(bx - NB*NCH - 16, cx, tw, tb, T);
    else if (bx < NB*NCH + 16 + 256 + 42) initC_body(bx - NB*NCH - 16 - 256, cw, cb, C);
    else prepw_body(bx - NB*NCH - 16 - 256 - 42,
                    ctq, ctk, ctv, cto, tcq, tck, tcv, tco,
                    caq, cak, cav, cao, enw, arena);
}

// Pre-phase 2: trange + cperm + initU
__global__ __launch_bounds__(256)
void k_pre4(const int* tind, int* lo_t, int* hi_t, int L, int gTr,
            const int* cind, int* invp, int* clo, int* chi,
            const float* uval, const float* uind, const float* mkb,
            const float* ew, const float* eb, short* U, int BL)
{
    int bx = blockIdx.x;
    if (bx < gTr) trange_body(bx, tind, lo_t, hi_t, L);
    else if (bx < gTr + NB) cperm_body(bx - gTr, cind, invp, clo, chi, L);
    else initU_body(bx - gTr - NB, uval, uind, mkb, ew, eb, U, BL);
}

// Phase 1: ct-kv + ct-q + tc-kv + tc-q  (kv GEMMs use M-tile 32)
__global__ __launch_bounds__(256)
void k_phase1(int g0, int g1, int g2,
              const short* T1, const int* tind, const short* U,
              const short* wkct, const float* bkct, const short* wvct, const float* bvct,
              unsigned* KVct, const int* invp,
              const short* C1, const short* wqct, const float* bqct, short* qC,
              const int* cind,
              const short* wktc, const float* bktc, const short* wvtc, const float* bvtc,
              unsigned* KVtc,
              const short* wqtc, const float* bqtc, short* qT,
              int BL, int L)
{
    __shared__ __align__(16) char smem[23040];
    int bx = blockIdx.x;
    if (bx < g0) {
        mgemm_kv32_body<2>(smem, bx, Seg{T1,tind,SS}, Seg{U,nullptr,0},
            wkct, bkct, wvct, bvct, KVct, BL, L, invp);
    } else if (bx < g0+g1) {
        mgemm_body<1,0>(smem, bx-g0, Seg{C1,nullptr,0}, Seg{nullptr,nullptr,0},
            Seg{nullptr,nullptr,0}, wqct, bqct, qC, NB*NDV, 1, nullptr);
    } else if (bx < g0+g1+g2) {
        mgemm_kv32_body<2>(smem, bx-g0-g1, Seg{C1,cind,NDV}, Seg{U,nullptr,0},
            wktc, bktc, wvtc, bvtc, KVtc, BL, L, nullptr);
    } else {
        mgemm_body<1,0>(smem, bx-g0-g1-g2, Seg{T1,nullptr,0}, Seg{nullptr,nullptr,0},
            Seg{nullptr,nullptr,0}, wqtc, bqtc, qT, NB*SS, 1, nullptr);
    }
}

// Phase 2: sattn ct + sattn tc
__global__ __launch_bounds__(256)
void k_phase2(int g0, const short* qC, const unsigned* KVct, short* oC,
              const int* clo, const int* chi, int L,
              const short* qT, const unsigned* KVtc, short* oT,
              const int* lo_t, const int* hi_t)
{
    int bx = blockIdx.x;
    if (bx < g0) sattn_body<2>(bx, qC, KVct, oC, NDV, L, clo, chi);
    else         sattn_body<1>(bx-g0, qT, KVtc, oT, SS, L, lo_t, hi_t);
}

// Phase 3: fused ct-o-proj + ca q/k/v | o-tc -> T2b | en -> Unew
__global__ __launch_bounds__(256)
void k_phase3(int g0, int g1,
              const short* oC, const short* woct, const float* boct,
              const short* wq_ca, const float* bq_ca,
              const short* wk_ca, const float* bk_ca,
              const short* wv_ca, const float* bv_ca,
              short* qC, unsigned* kvCa,
              const short* oT, const short* wotc, const float* botc, short* T2b,
              const short* U, const short* T1, const int* tind,
              const short* C1, const int* cind,
              const short* wen, const float* ben, short* Unew, const float* mkb,
              int BL, int L)
{
    __shared__ __align__(16) char smem[32768];
    int bx = blockIdx.x;
    if (bx < g0)
        octca_body(smem, bx, oC, woct, boct, wq_ca, bq_ca, wk_ca, bk_ca,
                   wv_ca, bv_ca, qC, kvCa, NB*NDV);
    else if (bx < g0+g1)
        mgemm_body<1,2>(smem, bx-g0, Seg{oT,nullptr,0}, Seg{nullptr,nullptr,0},
            Seg{nullptr,nullptr,0}, wotc, botc, T2b, NB*SS, 1, nullptr);
    else
        mgemm_body<3,3>(smem, bx-g0-g1, Seg{U,nullptr,0}, Seg{T1,tind,SS},
            Seg{C1,cind,NDV}, wen, ben, Unew, BL, L, mkb);
}

// Phase 4: fused ca attention + o-proj. One block per (b, qi) channel row.
__global__ __launch_bounds__(256)
void k_ca_fused(const short* __restrict__ qC, const unsigned* __restrict__ kv,
                const short* __restrict__ wo, const float* __restrict__ bo,
                short* __restrict__ C1)
{
    __shared__ __align__(16) short os[NKD];
    const int row = blockIdx.x;          // b*NDV + qi
    const int b = row / NDV;
    const int tid = threadIdx.x;
    const int h = tid >> 6;              // wave = head
    const int lane = tid & 63;
    const int d = lane & 31;
    const int half = lane >> 5;
    const float scale = 0.088388347648318447f;   // 1/sqrt(128)

    const float qv = bfs2f(qC[(size_t)row*NKD + h*DH + d]);
    const unsigned* kb = kv + (size_t)b*NDV*NKD + h*DH + d;

    float m = -INFINITY, ssum = 0.f, acc = 0.f;
    for (int l0 = 0; l0 < NDV; l0 += 2) {
        int l = l0 + half;
        unsigned ur = kb[(size_t)l*NKD];
        float kr = bf2f(ur & 0xffffu);
        float vr = bf2f(ur >> 16);
        float partial = qv * kr;
        #pragma unroll
        for (int off = 16; off; off >>= 1) partial += __shfl_xor(partial, off);
        float s = partial * scale;
        float mn = fmaxf(m, s);
        float corr = __expf(m - mn);
        float p = __expf(s - mn);
        ssum = ssum * corr + p;
        acc  = acc  * corr + p * vr;
        m = mn;
    }
    float mo = __shfl_xor(m, 32);
    float M = fmaxf(m, mo);
    float corr = (m > -1e30f) ? __expf(m - M) : 0.f;
    ssum *= corr; acc *= corr;
    ssum += __shfl_xor(ssum, 32);
    acc  += __shfl_xor(acc, 32);
    if (half == 0) {
        float res = (ssum > 0.f) ? acc / ssum : 0.f;
        os[h*DH + d] = f2bf(qv + res);
    }
    __syncthreads();

    const int n = tid >> 1;
    const int ks = (tid & 1) * 64;
    float a = 0.f;
    const short* wrow = wo + (size_t)n*NKD + ks;
    #pragma unroll
    for (int kk = 0; kk < 64; kk += 8) {
        short8 o8 = *(short8*)&os[ks + kk];
        short8 w8 = *(const short8*)(wrow + kk);
        #pragma unroll
        for (int j = 0; j < 8; j++) a += bfs2f(o8[j]) * bfs2f(w8[j]);
    }
    a += __shfl_xor(a, 1);
    if ((tid & 1) == 0) {
        float val = a + bo[n];
        val = bfs2f(os[n]) + fmaxf(val, 0.f);
        C1[(size_t)row*NKD + n] = f2bf(val);
    }
}

// Final head with inline gathers of k_t, k_c (bf16 inputs)
__global__ __launch_bounds__(256)
void k_out(const short* __restrict__ U, const short* __restrict__ T1,
           const short* __restrict__ C1, const int* __restrict__ tind,
           const int* __restrict__ cind, const float* __restrict__ ow,
           const float* __restrict__ obp, float* __restrict__ out,
           int BL, int L)
{
    int row = blockIdx.x * 4 + (threadIdx.x >> 6);
    int lane = threadIdx.x & 63;
    if (row >= BL) return;
    int b = row / L;
    int ti = tind[row]; if (ti < 0) ti = 0;
    int ci = cind[row]; if (ci < 0) ci = 0;
    const short* u = U + (size_t)row*NKD;
    const short* a = T1 + ((size_t)(b*SS + ti))*NKD;
    const short* c = C1 + ((size_t)(b*NDV + ci))*NKD;
    float s = bfs2f(u[lane])*ow[lane]     + bfs2f(u[lane+64])*ow[lane+64]
            + bfs2f(a[lane])*ow[128+lane] + bfs2f(a[lane+64])*ow[192+lane]
            + bfs2f(c[lane])*ow[256+lane] + bfs2f(c[lane+64])*ow[320+lane];
    #pragma unroll
    for (int off = 32; off; off >>= 1) s += __shfl_down(s, off);
    if (lane == 0) out[row] = s + obp[0];
}

// ---------------------------------------------------------------------------
extern "C" void kernel_launch(void* const* d_in, const int* in_sizes, int n_in,
                              void* d_out, int out_size, void* d_ws, size_t ws_size,
                              hipStream_t stream)
{
    const float* cx     = (const float*)d_in[0];
    const float* value  = (const float*)d_in[1];
    const float* maskp  = (const float*)d_in[2];
    const float* tval   = (const float*)d_in[3];
    const float* tmaskp = (const float*)d_in[4];
    const float* w0     = (const float*)d_in[5];
    const float* b0     = (const float*)d_in[6];
    const float* edge_w = (const float*)d_in[7];
    const float* edge_b = (const float*)d_in[8];
    const float* chan_w = (const float*)d_in[9];
    const float* chan_b = (const float*)d_in[10];
    const float* time_w = (const float*)d_in[11];
    const float* time_b = (const float*)d_in[12];
    const float* ct_wq = (const float*)d_in[13];
    const float* ct_bq = (const float*)d_in[14];
    const float* ct_wk = (const float*)d_in[15];
    const float* ct_bk = (const float*)d_in[16];
    const float* ct_wv = (const float*)d_in[17];
    const float* ct_bv = (const float*)d_in[18];
    const float* ct_wo = (const float*)d_in[19];
    const float* ct_bo = (const float*)d_in[20];
    const float* tc_wq = (const float*)d_in[21];
    const float* tc_bq = (const float*)d_in[22];
    const float* tc_wk = (const float*)d_in[23];
    const float* tc_bk = (const float*)d_in[24];
    const float* tc_wv = (const float*)d_in[25];
    const float* tc_bv = (const float*)d_in[26];
    const float* tc_wo = (const float*)d_in[27];
    const float* tc_bo = (const float*)d_in[28];
    const float* ca_wq = (const float*)d_in[29];
    const float* ca_bq = (const float*)d_in[30];
    const float* ca_wk = (const float*)d_in[31];
    const float* ca_bk = (const float*)d_in[32];
    const float* ca_wv = (const float*)d_in[33];
    const float* ca_bv = (const float*)d_in[34];
    const float* ca_wo = (const float*)d_in[35];
    const float* ca_bo = (const float*)d_in[36];
    const float* en_w  = (const float*)d_in[37];
    const float* en_b  = (const float*)d_in[38];
    const float* out_w = (const float*)d_in[39];
    const float* out_b = (const float*)d_in[40];

    const int BL = out_size / 3;     // B * full_len
    const int L  = BL / NB;

    char* p = (char*)d_ws;
    auto alloc = [&](size_t n) { char* r = p; p += (n + 255) & ~(size_t)255; return r; };
    int*      tind   = (int*)  alloc((size_t)BL*4);
    int*      cind   = (int*)  alloc((size_t)BL*4);
    float*    mkb    = (float*)alloc((size_t)BL*4);
    float*    uval   = (float*)alloc((size_t)BL*4);
    float*    uind   = (float*)alloc((size_t)BL*4);
    int*      lo_t   = (int*)  alloc((size_t)NB*SS*4);
    int*      hi_t   = (int*)  alloc((size_t)NB*SS*4);
    int*      clo    = (int*)  alloc((size_t)NB*NDV*4);
    int*      chi    = (int*)  alloc((size_t)NB*NDV*4);
    int*      invp   = (int*)  alloc((size_t)BL*4);
    short*    waren  = (short*)alloc((size_t)W_TOTAL*2);
    short*    U    = (short*)alloc((size_t)BL*NKD*2);
    short*    Unew = (short*)alloc((size_t)BL*NKD*2);
    unsigned* KVct = (unsigned*)alloc((size_t)BL*NKD*4);
    unsigned* KVtc = (unsigned*)alloc((size_t)BL*NKD*4);
    unsigned* kvCa = (unsigned*)alloc((size_t)NB*NDV*NKD*4);
    short*    T1   = (short*)alloc((size_t)NB*SS*NKD*2);
    short*    T2b  = (short*)alloc((size_t)NB*SS*NKD*2);
    short*    qT   = (short*)alloc((size_t)NB*SS*NKD*2);
    short*    oT   = (short*)alloc((size_t)NB*SS*NKD*2);
    short*    C1   = (short*)alloc((size_t)NB*NDV*NKD*2);
    short*    qC   = (short*)alloc((size_t)NB*NDV*NKD*2);
    short*    oC   = (short*)alloc((size_t)NB*NDV*NKD*2);

    float* outMain = (float*)d_out;
    float* outTU = outMain + BL;
    float* outTM = outMain + 2*BL;

    // weight arena offsets (shorts)
    const size_t OCTQ=0, OCTK=49152, OCTV=147456, OCTO=245760;
    const size_t OTCQ=294912, OTCK=344064, OTCV=442368, OTCO=540672;
    const size_t OCAQ=589824, OCAK=638976, OCAV=688128, OCAO=737280, OEN=786432;

    // Pre-phases (2 dispatches)
    k_pre_all<<<NB*NCH + 16 + 256 + 42 + W_TOTAL/256, 256, 0, stream>>>(
        cx, value, maskp, tval, tmaskp, w0, b0, L,
        tind, cind, mkb, uval, uind, outTU, outTM,
        lo_t, hi_t, time_w, time_b, T1, chan_w, chan_b, C1,
        ct_wq, ct_wk, ct_wv, ct_wo, tc_wq, tc_wk, tc_wv, tc_wo,
        ca_wq, ca_wk, ca_wv, ca_wo, en_w, waren);
    {
        const int gTr = (NB*L + 255)/256;
        const int gU  = (BL*16 + 255)/256;
        k_pre4<<<gTr + NB + gU, 256, 0, stream>>>(
            tind, lo_t, hi_t, L, gTr, cind, invp, clo, chi,
            uval, uind, mkb, edge_w, edge_b, U, BL);
    }

    const int gBL  = (BL + 127)/128;
    const int gKV  = (BL + 31)/32;       // M-tile 32
    const int gC   = (NB*NDV + 127)/128;
    const int gT   = (NB*SS + 127)/128;
    const int gCa  = (NB*NDV + 63)/64;
    const int aC2  = NB*NDV*NHD*2/4;     // SPLIT=2
    const int aTC  = NB*SS*NHD/4;        // SPLIT=1

    for (int i = 0; i < NLAY; i++) {
        const size_t bOff = (size_t)i*NKD;
        const short* wq_ct = waren + OCTQ + (size_t)i*128*128;
        const short* wk_ct = waren + OCTK + (size_t)i*256*128;
        const short* wv_ct = waren + OCTV + (size_t)i*256*128;
        const short* wo_ct = waren + OCTO + (size_t)i*128*128;
        const short* wq_tc = waren + OTCQ + (size_t)i*128*128;
        const short* wk_tc = waren + OTCK + (size_t)i*256*128;
        const short* wv_tc = waren + OTCV + (size_t)i*256*128;
        const short* wo_tc = waren + OTCO + (size_t)i*128*128;
        const short* wq_ca = waren + OCAQ + (size_t)i*128*128;
        const short* wk_ca = waren + OCAK + (size_t)i*128*128;
        const short* wv_ca = waren + OCAV + (size_t)i*128*128;
        const short* wo_ca = waren + OCAO + (size_t)i*128*128;
        const short* w_en  = waren + OEN  + (size_t)i*384*128;

        // P1: q/kv projections from (T1, C1, U)
        k_phase1<<<gKV + gC + gKV + gT, 256, 0, stream>>>(
            gKV, gC, gKV,
            T1, tind, U,
            wk_ct, ct_bk + bOff, wv_ct, ct_bv + bOff, KVct, invp,
            C1, wq_ct, ct_bq + bOff, qC,
            cind, wk_tc, tc_bk + bOff, wv_tc, tc_bv + bOff, KVtc,
            wq_tc, tc_bq + bOff, qT, BL, L);
        // P2: both segmented attentions
        k_phase2<<<aC2 + aTC, 256, 0, stream>>>(
            aC2, qC, KVct, oC, clo, chi, L, qT, KVtc, oT, lo_t, hi_t);
        // P3: fused ct-o-proj+ca-kvq | o-tc | en
        k_phase3<<<gCa + gT + gBL, 256, 0, stream>>>(
            gCa, gT,
            oC, wo_ct, ct_bo + bOff,
            wq_ca, ca_bq + bOff, wk_ca, ca_bk + bOff, wv_ca, ca_bv + bOff,
            qC, kvCa,
            oT, wo_tc, tc_bo + bOff, T2b,
            U, T1, tind, C1, cind, w_en, en_b + bOff, Unew, mkb, BL, L);
        // P4: fused ca attention + o-proj (672 blocks — stays parallel)
        k_ca_fused<<<NB*NDV, 256, 0, stream>>>(qC, kvCa, wo_ca, ca_bo + bOff, C1);

        short* t = U;  U = Unew; Unew = t;
        t = T1; T1 = T2b; T2b = t;
    }

    k_out<<<(BL + 3)/4, 256, 0, stream>>>(U, T1, C1, tind, cind,
                                          out_w, out_b, outMain, BL, L);
}

// Round 16
// 443.349 us; speedup vs baseline: 1.0311x; 1.0311x over previous
//
#include <hip/hip_runtime.h>
#include <math.h>

#define NB   16
#define SS   256
#define DIMV 41
#define NDV  42
#define NKD  128
#define NHD  4
#define DH   32
#define NLAY 3
#define TOT  (SS*NDV)   // 10752 = 42 chunks of 256
#define NCH  42

typedef __attribute__((ext_vector_type(8))) short short8;
typedef __attribute__((ext_vector_type(4))) float floatx4;

__device__ __forceinline__ short f2bf(float x) {
    unsigned u = __float_as_uint(x);
    u += 0x7fff + ((u >> 16) & 1);          // RNE f32 -> bf16
    return (short)(u >> 16);
}
__device__ __forceinline__ float bfs2f(short s) {
    return __uint_as_float(((unsigned)(unsigned short)s) << 16);
}
__device__ __forceinline__ float bf2f(unsigned s) {
    return __uint_as_float(s << 16);
}

struct Seg { const short* ptr; const int* ind; int ns; };

__device__ __forceinline__ const short* seg_row(const Seg s, int gm, int Lb) {
    if (s.ind) {
        int b = gm / Lb;
        int id = s.ind[gm]; if (id < 0) id = 0;
        return s.ptr + ((size_t)b * s.ns + (size_t)id) * NKD;
    }
    return s.ptr + (size_t)gm * NKD;
}

// ===========================================================================
// Device bodies
// ===========================================================================

__device__ __forceinline__ void zero_body(int bx, int* __restrict__ lo_t,
                                          int* __restrict__ hi_t)
{
    int i = bx*256 + threadIdx.x;
    if (i < NB*SS) { lo_t[i] = 0; hi_t[i] = 0; }
}

__device__ __forceinline__ void initT_body(int bx, const float* __restrict__ cx,
                                           const float* __restrict__ tw,
                                           const float* __restrict__ tb,
                                           short* __restrict__ T)
{
    int i = bx * 256 + threadIdx.x;
    if (i >= NB*SS*16) return;
    int row = i >> 4;
    int k = (i & 15) << 3;
    float t = cx[row];
    short8 r;
    #pragma unroll
    for (int j = 0; j < 8; j++) r[j] = f2bf(sinf(t*tw[k+j] + tb[k+j]));
    *(short8*)(T + (size_t)row*NKD + k) = r;
}

__device__ __forceinline__ void initC_body(int bx, const float* __restrict__ cw,
                                           const float* __restrict__ cb,
                                           short* __restrict__ C)
{
    int i = bx * 256 + threadIdx.x;
    if (i >= NB*NDV*16) return;
    int row = i >> 4;
    int c = row % NDV;
    int k = (i & 15) << 3;
    short8 r;
    #pragma unroll
    for (int j = 0; j < 8; j++) r[j] = f2bf(fmaxf(cw[(size_t)c*NKD + k+j] + cb[k+j], 0.f));
    *(short8*)(C + (size_t)row*NKD + k) = r;
}

template<int Kg>
__device__ __forceinline__ void prep1(const float* __restrict__ src,
                                      short* __restrict__ dst, int rel)
{
    const int per = Kg*128;
    int i = rel / per; int r2 = rel - i*per;
    int n = r2 / Kg;   int k = r2 - n*Kg;
    dst[rel] = f2bf(src[(size_t)i*per + (size_t)k*128 + n]);
}

#define W_TOTAL 933888
__device__ __forceinline__ void prepw_body(int bx,
    const float* ctq, const float* ctk, const float* ctv, const float* cto,
    const float* tcq, const float* tck, const float* tcv, const float* tco,
    const float* caq, const float* cak, const float* cav, const float* cao,
    const float* enw, short* __restrict__ arena)
{
    int idx = bx*256 + threadIdx.x;
    if (idx >= W_TOTAL) return;
    if      (idx < 49152 ) prep1<128>(ctq, arena + 0,      idx - 0);
    else if (idx < 147456) prep1<256>(ctk, arena + 49152,  idx - 49152);
    else if (idx < 245760) prep1<256>(ctv, arena + 147456, idx - 147456);
    else if (idx < 294912) prep1<128>(cto, arena + 245760, idx - 245760);
    else if (idx < 344064) prep1<128>(tcq, arena + 294912, idx - 294912);
    else if (idx < 442368) prep1<256>(tck, arena + 344064, idx - 344064);
    else if (idx < 540672) prep1<256>(tcv, arena + 442368, idx - 442368);
    else if (idx < 589824) prep1<128>(tco, arena + 540672, idx - 540672);
    else if (idx < 638976) prep1<128>(caq, arena + 589824, idx - 589824);
    else if (idx < 688128) prep1<128>(cak, arena + 638976, idx - 638976);
    else if (idx < 737280) prep1<128>(cav, arena + 688128, idx - 688128);
    else if (idx < 786432) prep1<128>(cao, arena + 737280, idx - 737280);
    else                   prep1<384>(enw, arena + 786432, idx - 786432);
}

// compactC with in-block chunk counting (compactA + compactB folded in)
__device__ __forceinline__ void compactC_body(int blk,
              const float* __restrict__ cx, const float* __restrict__ value,
              const float* __restrict__ maskp, const float* __restrict__ tval,
              const float* __restrict__ tmaskp, const float* __restrict__ w0p,
              const float* __restrict__ b0p, int L,
              int* __restrict__ tind, int* __restrict__ cind,
              float* __restrict__ mkb, float* __restrict__ uval,
              float* __restrict__ uind,
              float* __restrict__ outTU, float* __restrict__ outTM)
{
    const int b = blk / NCH, ch = blk % NCH;
    const int tid = threadIdx.x, lane = tid & 63, wv = tid >> 6;
    __shared__ int cc[NCH];
    __shared__ int wsum[4];
    __shared__ int s_off, s_cnt;

    const int idx = ch * 256 + tid;
    const int s = idx / NDV, c = idx % NDV;
    float mval = (c < DIMV) ? maskp[((size_t)b*SS + s)*DIMV + c] : 1.0f;
    int m = (mval != 0.0f) ? 1 : 0;
    int x = m;
    #pragma unroll
    for (int off = 1; off < 64; off <<= 1) {
        int y = __shfl_up(x, off);
        if (lane >= off) x += y;
    }
    if (lane == 63) wsum[wv] = x;

    for (int j = wv; j < NCH; j += 4) {
        int cnt = 0;
        #pragma unroll
        for (int i = 0; i < 4; i++) {
            int idx2 = j*256 + lane + 64*i;
            int s2 = idx2 / NDV, c2 = idx2 % NDV;
            float m2 = (c2 < DIMV) ? maskp[((size_t)b*SS + s2)*DIMV + c2] : 1.0f;
            cnt += (m2 != 0.0f) ? 1 : 0;
        }
        #pragma unroll
        for (int off = 32; off; off >>= 1) cnt += __shfl_down(cnt, off);
        if (lane == 0) cc[j] = cnt;
    }
    __syncthreads();
    if (tid < 64) {
        int v2 = (tid < NCH) ? cc[tid] : 0;
        int x2 = v2;
        #pragma unroll
        for (int off = 1; off < 64; off <<= 1) {
            int y2 = __shfl_up(x2, off);
            if (tid >= off) x2 += y2;
        }
        if (tid == ch) s_off = x2 - v2;
        if (tid == 63) s_cnt = x2;
    }
    __syncthreads();
    int wbase = 0;
    for (int w = 0; w < wv; w++) wbase += wsum[w];
    const int excl = x - m + wbase;
    const int vbefore = s_off + excl;
    const int cnt = s_cnt;
    const int pos = m ? vbefore : (cnt + (idx - vbefore));
    if (pos < L) {
        const float w0 = w0p[0], b0 = b0p[0];
        float te = w0 * cx[(size_t)b*SS + s] + b0;
        float vf, tvf, tmf;
        if (c < DIMV) {
            size_t o = ((size_t)b*SS + s)*DIMV + c;
            vf = value[o]; tvf = tval[o]; tmf = tmaskp[o];
        } else { vf = te; tvf = te; tmf = 0.0f; }
        size_t p = (size_t)b*L + pos;
        if (m) {
            tind[p] = s; cind[p] = c; mkb[p] = 1.0f;
            uval[p] = vf; uind[p] = tmf;
            outTU[p] = tvf; outTM[p] = tmf;
        } else {
            tind[p] = -1; cind[p] = -1; mkb[p] = 0.0f;
            uval[p] = 0.0f; uind[p] = 1.0f;
            outTU[p] = 0.0f; outTM[p] = 0.0f;
        }
    }
}

__device__ __forceinline__ void trange_body(int bx, const int* __restrict__ tind,
                                            int* __restrict__ lo_t,
                                            int* __restrict__ hi_t, int L)
{
    int p = bx*256 + threadIdx.x;
    if (p >= NB*L) return;
    int b = p / L, l = p - b*L;
    int t = tind[p];
    if (t < 0) return;
    int tp = (l > 0) ? tind[p-1] : -999;
    int tn = (l+1 < L) ? tind[p+1] : -999;
    if (tp != t) lo_t[b*SS + t] = l;
    if (tn != t) hi_t[b*SS + t] = l+1;
}

__device__ __forceinline__ void cperm_body(int b, const int* __restrict__ cind,
                                           int* __restrict__ invp,
                                           int* __restrict__ clo,
                                           int* __restrict__ chi, int L)
{
    __shared__ int hist[NDV];
    __shared__ int base[NDV];
    __shared__ int padc, cntsh;
    const int tid = threadIdx.x;
    if (tid < NDV) hist[tid] = 0;
    if (tid == 0) padc = 0;
    __syncthreads();
    for (int l = tid; l < L; l += 256) {
        int c = cind[(size_t)b*L + l];
        if (c >= 0) atomicAdd(&hist[c], 1);
    }
    __syncthreads();
    if (tid == 0) {
        int run = 0;
        for (int c = 0; c < NDV; c++) {
            base[c] = run; clo[b*NDV + c] = run;
            run += hist[c]; chi[b*NDV + c] = run;
        }
        cntsh = run;
    }
    __syncthreads();
    if (tid < NDV) hist[tid] = 0;
    __syncthreads();
    const int cnt = cntsh;
    for (int l = tid; l < L; l += 256) {
        int c = cind[(size_t)b*L + l];
        int pos;
        if (c >= 0) pos = base[c] + atomicAdd(&hist[c], 1);
        else        pos = cnt + atomicAdd(&padc, 1);
        invp[(size_t)b*L + l] = b*L + pos;
    }
}

__device__ __forceinline__ void initU_body(int bx, const float* __restrict__ uval,
                                           const float* __restrict__ uind,
                                           const float* __restrict__ mkb,
                                           const float* __restrict__ ew,
                                           const float* __restrict__ eb,
                                           short* __restrict__ U, int BL)
{
    int i = bx * 256 + threadIdx.x;
    if (i >= BL*16) return;
    int row = i >> 4;
    int k = (i & 15) << 3;
    float uv = uval[row], ui = uind[row], m = mkb[row];
    short8 r;
    #pragma unroll
    for (int j = 0; j < 8; j++)
        r[j] = f2bf(fmaxf(uv*ew[k+j] + ui*ew[NKD+k+j] + eb[k+j], 0.f) * m);
    *(short8*)(U + (size_t)row*NKD + k) = r;
}

// ---------------------------------------------------------------------------
// MFMA GEMM body (M-tile 128), bf16 activations in/out. smem >= 20480
// MODE 0: D = acc+b ; MODE 2: D = A0 + relu(acc+b) ; MODE 3: relu(A0+acc+b)*mk
// ---------------------------------------------------------------------------
template<int NSEG, int MODE>
__device__ __forceinline__ void mgemm_body(char* smem, int bx,
           Seg s0, Seg s1, Seg s2, const short* __restrict__ Wt,
           const float* __restrict__ bias, short* __restrict__ D,
           int M, int Lb, const float* __restrict__ mkp)
{
    short (*As)[40] = (short (*)[40])smem;
    short (*Bs)[40] = (short (*)[40])(smem + 10240);
    const int bm = bx * 128;
    const int tid = threadIdx.x;
    const int wv = tid >> 6;
    const int lane = tid & 63;
    const int quad = lane >> 4;
    const int l16 = lane & 15;
    const int K = NSEG * 128;
    floatx4 acc[2][8];
    #pragma unroll
    for (int i = 0; i < 2; i++)
        #pragma unroll
        for (int j = 0; j < 8; j++) acc[i][j] = (floatx4){0.f,0.f,0.f,0.f};

    const int arow = tid >> 1;
    const int acol = (tid & 1) * 16;
    int gmc = bm + arow; if (gmc > M-1) gmc = M-1;
    const short* rowp0 = seg_row(s0, gmc, Lb);
    const short* rowp1 = (NSEG > 1) ? seg_row(s1, gmc, Lb) : nullptr;
    const short* rowp2 = (NSEG > 2) ? seg_row(s2, gmc, Lb) : nullptr;

    for (int k0 = 0; k0 < K; k0 += 32) {
        {
            const short* rp;
            if (NSEG == 1) rp = rowp0;
            else if (NSEG == 2) rp = (k0 < 128) ? rowp0 : rowp1;
            else rp = (k0 < 128) ? rowp0 : ((k0 < 256) ? rowp1 : rowp2);
            const int ks = k0 & 127;
            const short* src = rp + ks + acol;
            *(short8*)&As[arow][acol]   = *(const short8*)(src);
            *(short8*)&As[arow][acol+8] = *(const short8*)(src+8);
        }
        {
            const short* src = Wt + (size_t)arow*K + k0 + acol;
            *(short8*)&Bs[arow][acol]   = *(const short8*)(src);
            *(short8*)&Bs[arow][acol+8] = *(const short8*)(src+8);
        }
        __syncthreads();
        short8 af0 = *(short8*)&As[wv*32 + l16][quad*8];
        short8 af1 = *(short8*)&As[wv*32 + 16 + l16][quad*8];
        #pragma unroll
        for (int nf = 0; nf < 8; nf++) {
            short8 bf = *(short8*)&Bs[nf*16 + l16][quad*8];
            acc[0][nf] = __builtin_amdgcn_mfma_f32_16x16x32_bf16(af0, bf, acc[0][nf], 0, 0, 0);
            acc[1][nf] = __builtin_amdgcn_mfma_f32_16x16x32_bf16(af1, bf, acc[1][nf], 0, 0, 0);
        }
        __syncthreads();
    }
    #pragma unroll
    for (int mf = 0; mf < 2; mf++) {
        #pragma unroll
        for (int r = 0; r < 4; r++) {
            int gm = bm + wv*32 + mf*16 + quad*4 + r;
            if (gm < M) {
                float mk = (MODE == 3) ? mkp[gm] : 0.f;
                const short* res = (MODE == 2 || MODE == 3) ? seg_row(s0, gm, Lb) : nullptr;
                #pragma unroll
                for (int nf = 0; nf < 8; nf++) {
                    int gn = nf*16 + l16;
                    float val = acc[mf][nf][r] + bias[gn];
                    if (MODE == 2) val = bfs2f(res[gn]) + fmaxf(val, 0.f);
                    else if (MODE == 3) val = fmaxf(bfs2f(res[gn]) + val, 0.f) * mk;
                    D[(size_t)gm*NKD + gn] = f2bf(val);
                }
            }
        }
    }
}

// ---------------------------------------------------------------------------
// Dual-output KV GEMM body (M-tile 64): packed bf16 (k | v<<16). smem >= 25600
// ---------------------------------------------------------------------------
template<int NSEG>
__device__ __forceinline__ void mgemm_kv_body(char* smem, int bx,
              Seg s0, Seg s1,
              const short* __restrict__ Wk, const float* __restrict__ bk,
              const short* __restrict__ Wv, const float* __restrict__ bv,
              unsigned* __restrict__ KV, int M, int Lb, const int* __restrict__ rmap)
{
    short (*As)[40] = (short (*)[40])smem;
    short (*Bk_)[40] = (short (*)[40])(smem + 5120);
    short (*Bv_)[40] = (short (*)[40])(smem + 15360);
    const int bm = bx * 64;
    const int tid = threadIdx.x;
    const int wv = tid >> 6;
    const int lane = tid & 63;
    const int quad = lane >> 4;
    const int l16 = lane & 15;
    const int K = NSEG * 128;
    floatx4 acck[8], accv[8];
    #pragma unroll
    for (int j = 0; j < 8; j++) {
        acck[j] = (floatx4){0.f,0.f,0.f,0.f};
        accv[j] = (floatx4){0.f,0.f,0.f,0.f};
    }

    const int arow = tid >> 2;
    const int acol = (tid & 3) * 8;
    const int brow = tid >> 1;
    const int bcol = (tid & 1) * 16;
    int gmc = bm + arow; if (gmc > M-1) gmc = M-1;
    const short* rowp0 = seg_row(s0, gmc, Lb);
    const short* rowp1 = (NSEG > 1) ? seg_row(s1, gmc, Lb) : nullptr;

    for (int k0 = 0; k0 < K; k0 += 32) {
        {
            const short* rp = (NSEG == 1) ? rowp0 : ((k0 < 128) ? rowp0 : rowp1);
            const int ks = k0 & 127;
            *(short8*)&As[arow][acol] = *(const short8*)(rp + ks + acol);
        }
        {
            const short* sk = Wk + (size_t)brow*K + k0 + bcol;
            *(short8*)&Bk_[brow][bcol]   = *(const short8*)(sk);
            *(short8*)&Bk_[brow][bcol+8] = *(const short8*)(sk+8);
            const short* sv = Wv + (size_t)brow*K + k0 + bcol;
            *(short8*)&Bv_[brow][bcol]   = *(const short8*)(sv);
            *(short8*)&Bv_[brow][bcol+8] = *(const short8*)(sv+8);
        }
        __syncthreads();
        short8 af = *(short8*)&As[wv*16 + l16][quad*8];
        #pragma unroll
        for (int nf = 0; nf < 8; nf++) {
            short8 bfk = *(short8*)&Bk_[nf*16 + l16][quad*8];
            acck[nf] = __builtin_amdgcn_mfma_f32_16x16x32_bf16(af, bfk, acck[nf], 0, 0, 0);
            short8 bfv = *(short8*)&Bv_[nf*16 + l16][quad*8];
            accv[nf] = __builtin_amdgcn_mfma_f32_16x16x32_bf16(af, bfv, accv[nf], 0, 0, 0);
        }
        __syncthreads();
    }
    #pragma unroll
    for (int r = 0; r < 4; r++) {
        int gm = bm + wv*16 + quad*4 + r;
        if (gm < M) {
            int orow = rmap ? rmap[gm] : gm;
            #pragma unroll
            for (int nf = 0; nf < 8; nf++) {
                int gn = nf*16 + l16;
                float kf = acck[nf][r] + bk[gn];
                float vf = accv[nf][r] + bv[gn];
                unsigned pk = (unsigned)(unsigned short)f2bf(kf)
                            | ((unsigned)(unsigned short)f2bf(vf) << 16);
                KV[(size_t)orow*NKD + gn] = pk;
            }
        }
    }
}

// ---------------------------------------------------------------------------
// Fused ct-o-proj + ca q/k/v (M-tile 64): C2 = oC + relu(oC@wo+bo) lives only
// in LDS; q -> qC (bf16), k/v -> packed kvCa. smem >= 32768.
// ---------------------------------------------------------------------------
__device__ __forceinline__ void octca_body(char* smem, int bx,
    const short* __restrict__ oC,
    const short* __restrict__ wo, const float* __restrict__ bo,
    const short* __restrict__ wq, const float* __restrict__ bq,
    const short* __restrict__ wk, const float* __restrict__ bk,
    const short* __restrict__ wv, const float* __restrict__ bv,
    short* __restrict__ qC, unsigned* __restrict__ KV, int M)
{
    short (*C2t)[136] = (short (*)[136])smem;            // 17408 B
    short (*Bs)[40]   = (short (*)[40])(smem + 17408);   // 10240 B
    short (*As)[40]   = (short (*)[40])(smem + 27648);   // 5120 B
    const int bm = bx * 64;
    const int tid = threadIdx.x;
    const int wv_ = tid >> 6;
    const int lane = tid & 63;
    const int quad = lane >> 4;
    const int l16 = lane & 15;
    const int arow = tid >> 2;
    const int acol = (tid & 3) * 8;
    const int brow = tid >> 1;
    const int bcol = (tid & 1) * 16;
    int gmc = bm + arow; if (gmc > M-1) gmc = M-1;
    const short* rowp = oC + (size_t)gmc * NKD;

    floatx4 acc[8];
    #pragma unroll
    for (int j = 0; j < 8; j++) acc[j] = (floatx4){0.f,0.f,0.f,0.f};
    for (int k0 = 0; k0 < 128; k0 += 32) {
        *(short8*)&As[arow][acol] = *(const short8*)(rowp + k0 + acol);
        const short* sw = wo + (size_t)brow*128 + k0 + bcol;
        *(short8*)&Bs[brow][bcol]   = *(const short8*)(sw);
        *(short8*)&Bs[brow][bcol+8] = *(const short8*)(sw+8);
        __syncthreads();
        short8 af = *(short8*)&As[wv_*16 + l16][quad*8];
        #pragma unroll
        for (int nf = 0; nf < 8; nf++) {
            short8 bf = *(short8*)&Bs[nf*16 + l16][quad*8];
            acc[nf] = __builtin_amdgcn_mfma_f32_16x16x32_bf16(af, bf, acc[nf], 0, 0, 0);
        }
        __syncthreads();
    }
    #pragma unroll
    for (int r = 0; r < 4; r++) {
        int lrow = wv_*16 + quad*4 + r;
        int gm = bm + lrow; int gmr = (gm > M-1) ? (M-1) : gm;
        const short* res = oC + (size_t)gmr*NKD;
        #pragma unroll
        for (int nf = 0; nf < 8; nf++) {
            int gn = nf*16 + l16;
            float val = acc[nf][r] + bo[gn];
            val = bfs2f(res[gn]) + fmaxf(val, 0.f);
            C2t[lrow][gn] = f2bf(val);
        }
    }
    __syncthreads();

    floatx4 acck[8];
    for (int proj = 0; proj < 3; proj++) {
        const short* W = (proj == 0) ? wq : ((proj == 1) ? wk : wv);
        floatx4 a2[8];
        #pragma unroll
        for (int j = 0; j < 8; j++) a2[j] = (floatx4){0.f,0.f,0.f,0.f};
        for (int k0 = 0; k0 < 128; k0 += 32) {
            const short* sw = W + (size_t)brow*128 + k0 + bcol;
            *(short8*)&Bs[brow][bcol]   = *(const short8*)(sw);
            *(short8*)&Bs[brow][bcol+8] = *(const short8*)(sw+8);
            __syncthreads();
            short8 af = *(short8*)&C2t[wv_*16 + l16][k0 + quad*8];
            #pragma unroll
            for (int nf = 0; nf < 8; nf++) {
                short8 bf = *(short8*)&Bs[nf*16 + l16][quad*8];
                a2[nf] = __builtin_amdgcn_mfma_f32_16x16x32_bf16(af, bf, a2[nf], 0, 0, 0);
            }
            __syncthreads();
        }
        if (proj == 0) {
            #pragma unroll
            for (int r = 0; r < 4; r++) {
                int gm = bm + wv_*16 + quad*4 + r;
                if (gm < M) {
                    #pragma unroll
                    for (int nf = 0; nf < 8; nf++) {
                        int gn = nf*16 + l16;
                        qC[(size_t)gm*NKD + gn] = f2bf(a2[nf][r] + bq[gn]);
                    }
                }
            }
        } else if (proj == 1) {
            #pragma unroll
            for (int j = 0; j < 8; j++) acck[j] = a2[j];
        } else {
            #pragma unroll
            for (int r = 0; r < 4; r++) {
                int gm = bm + wv_*16 + quad*4 + r;
                if (gm < M) {
                    #pragma unroll
                    for (int nf = 0; nf < 8; nf++) {
                        int gn = nf*16 + l16;
                        float kf = acck[nf][r] + bk[gn];
                        float vf = a2[nf][r] + bv[gn];
                        KV[(size_t)gm*NKD + gn] =
                            (unsigned)(unsigned short)f2bf(kf)
                          | ((unsigned)(unsigned short)f2bf(vf) << 16);
                    }
                }
            }
        }
    }
}

// ---------------------------------------------------------------------------
// Segmented attention body on packed bf16 KV, bf16 q/o. SPLIT waves/(b,q,h).
// ---------------------------------------------------------------------------
template<int SPLIT>
__device__ __forceinline__ void sattn_body(int bx,
                  const short* __restrict__ q, const unsigned* __restrict__ kvb,
                  short* __restrict__ o, int nq, int nkv,
                  const int* __restrict__ lo_arr, const int* __restrict__ hi_arr)
{
    __shared__ float sm_m[4], sm_s[4], sm_a[4][DH];
    const int wvid = threadIdx.x >> 6;
    int gtask = bx * 4 + wvid;
    int task = gtask / SPLIT;
    int part = gtask % SPLIT;
    if (task >= NB * nq * NHD) return;
    const int h = task & 3;
    const int bq = task >> 2;
    const int qi = bq % nq;
    const int b = bq / nq;
    const int lane = threadIdx.x & 63;
    const int d = lane & 31;
    const int half = lane >> 5;
    int lo = lo_arr ? lo_arr[b*nq + qi] : 0;
    int hi = hi_arr ? hi_arr[b*nq + qi] : nkv;
    if (SPLIT == 2) {
        int mid = lo + ((hi - lo + 1) >> 1);
        if (part == 0) hi = mid; else lo = mid;
    }
    const float scale = 0.088388347648318447f;   // 1/sqrt(128)

    const float qv = bfs2f(q[((size_t)(b*nq + qi))*NKD + h*DH + d]);
    const unsigned* kb = kvb + (size_t)b*nkv*NKD + h*DH + d;

    float m = -INFINITY, ssum = 0.f, acc = 0.f;
    for (int l0 = lo; l0 < hi; l0 += 8) {
        unsigned ur[4];
        #pragma unroll
        for (int j = 0; j < 4; j++) {
            int l = l0 + 2*j + half;
            bool ok = (l < hi);
            ur[j] = ok ? kb[(size_t)l*NKD] : 0u;
        }
        #pragma unroll
        for (int j = 0; j < 4; j++) {
            int l = l0 + 2*j + half;
            float kr = bf2f(ur[j] & 0xffffu);
            float vr = bf2f(ur[j] >> 16);
            float partial = qv * kr;
            #pragma unroll
            for (int off = 16; off; off >>= 1) partial += __shfl_xor(partial, off);
            float s = partial * scale;
            if (l < hi) {
                float mn = fmaxf(m, s);
                float corr = __expf(m - mn);
                float p = __expf(s - mn);
                ssum = ssum * corr + p;
                acc  = acc  * corr + p * vr;
                m = mn;
            }
        }
    }
    float mo = __shfl_xor(m, 32);
    float M = fmaxf(m, mo);
    float corr = (m > -1e30f) ? __expf(m - M) : 0.f;
    ssum *= corr; acc *= corr;
    ssum += __shfl_xor(ssum, 32);
    acc  += __shfl_xor(acc, 32);

    if (SPLIT == 1) {
        if (half == 0) {
            float res = (ssum > 0.f) ? acc / ssum : 0.f;
            o[((size_t)(b*nq + qi))*NKD + h*DH + d] = f2bf(qv + res);
        }
    } else {
        if (lane == 0) { sm_m[wvid] = M; sm_s[wvid] = ssum; }
        if (lane < DH) sm_a[wvid][lane] = acc;
        __syncthreads();
        if (part == 0 && lane < DH) {
            float m2 = sm_m[wvid+1], s2 = sm_s[wvid+1], a2 = sm_a[wvid+1][lane];
            float M2 = fmaxf(M, m2);
            float c1 = (M  > -1e30f) ? __expf(M  - M2) : 0.f;
            float c2 = (m2 > -1e30f) ? __expf(m2 - M2) : 0.f;
            float S = ssum * c1 + s2 * c2;
            float A = acc  * c1 + a2 * c2;
            float res = (S > 0.f) ? A / S : 0.f;
            float qv2 = bfs2f(q[((size_t)(b*nq + qi))*NKD + h*DH + lane]);
            o[((size_t)(b*nq + qi))*NKD + h*DH + lane] = f2bf(qv2 + res);
        }
    }
}

// ===========================================================================
// Kernels
// ===========================================================================

// Pre-phase 1 (everything independent): compactC-self + zero + initT + initC + prepw
__global__ __launch_bounds__(256)
void k_pre_all(const float* cx, const float* value, const float* maskp,
               const float* tval, const float* tmaskp, const float* w0p,
               const float* b0p, int L,
               int* tind, int* cind, float* mkb, float* uval, float* uind,
               float* outTU, float* outTM,
               int* lo_t, int* hi_t,
               const float* tw, const float* tb, short* T,
               const float* cw, const float* cb, short* C,
               const float* ctq, const float* ctk, const float* ctv, const float* cto,
               const float* tcq, const float* tck, const float* tcv, const float* tco,
               const float* caq, const float* cak, const float* cav, const float* cao,
               const float* enw, short* arena)
{
    int bx = blockIdx.x;
    if (bx < NB*NCH)
        compactC_body(bx, cx, value, maskp, tval, tmaskp, w0p, b0p, L,
                      tind, cind, mkb, uval, uind, outTU, outTM);
    else if (bx < NB*NCH + 16)  zero_body(bx - NB*NCH, lo_t, hi_t);
    else if (bx < NB*NCH + 16 + 256) initT_body(bx - NB*NCH - 16, cx, tw, tb, T);
    else if (bx < NB*NCH + 16 + 256 + 42) initC_body(bx - NB*NCH - 16 - 256, cw, cb, C);
    else prepw_body(bx - NB*NCH - 16 - 256 - 42,
                    ctq, ctk, ctv, cto, tcq, tck, tcv, tco,
                    caq, cak, cav, cao, enw, arena);
}

// Pre-phase 2: trange + cperm + initU
__global__ __launch_bounds__(256)
void k_pre4(const int* tind, int* lo_t, int* hi_t, int L, int gTr,
            const int* cind, int* invp, int* clo, int* chi,
            const float* uval, const float* uind, const float* mkb,
            const float* ew, const float* eb, short* U, int BL)
{
    int bx = blockIdx.x;
    if (bx < gTr) trange_body(bx, tind, lo_t, hi_t, L);
    else if (bx < gTr + NB) cperm_body(bx - gTr, cind, invp, clo, chi, L);
    else initU_body(bx - gTr - NB, uval, uind, mkb, ew, eb, U, BL);
}

// Phase 1: ct-kv + ct-q + tc-kv + tc-q  (kv GEMMs use M-tile 64)
__global__ __launch_bounds__(256)
void k_phase1(int g0, int g1, int g2,
              const short* T1, const int* tind, const short* U,
              const short* wkct, const float* bkct, const short* wvct, const float* bvct,
              unsigned* KVct, const int* invp,
              const short* C1, const short* wqct, const float* bqct, short* qC,
              const int* cind,
              const short* wktc, const float* bktc, const short* wvtc, const float* bvtc,
              unsigned* KVtc,
              const short* wqtc, const float* bqtc, short* qT,
              int BL, int L)
{
    __shared__ __align__(16) char smem[25600];
    int bx = blockIdx.x;
    if (bx < g0) {
        mgemm_kv_body<2>(smem, bx, Seg{T1,tind,SS}, Seg{U,nullptr,0},
            wkct, bkct, wvct, bvct, KVct, BL, L, invp);
    } else if (bx < g0+g1) {
        mgemm_body<1,0>(smem, bx-g0, Seg{C1,nullptr,0}, Seg{nullptr,nullptr,0},
            Seg{nullptr,nullptr,0}, wqct, bqct, qC, NB*NDV, 1, nullptr);
    } else if (bx < g0+g1+g2) {
        mgemm_kv_body<2>(smem, bx-g0-g1, Seg{C1,cind,NDV}, Seg{U,nullptr,0},
            wktc, bktc, wvtc, bvtc, KVtc, BL, L, nullptr);
    } else {
        mgemm_body<1,0>(smem, bx-g0-g1-g2, Seg{T1,nullptr,0}, Seg{nullptr,nullptr,0},
            Seg{nullptr,nullptr,0}, wqtc, bqtc, qT, NB*SS, 1, nullptr);
    }
}

// Phase 2: sattn ct + sattn tc
__global__ __launch_bounds__(256)
void k_phase2(int g0, const short* qC, const unsigned* KVct, short* oC,
              const int* clo, const int* chi, int L,
              const short* qT, const unsigned* KVtc, short* oT,
              const int* lo_t, const int* hi_t)
{
    int bx = blockIdx.x;
    if (bx < g0) sattn_body<2>(bx, qC, KVct, oC, NDV, L, clo, chi);
    else         sattn_body<1>(bx-g0, qT, KVtc, oT, SS, L, lo_t, hi_t);
}

// Phase 3: fused ct-o-proj + ca q/k/v | o-tc -> T2b | en -> Unew
__global__ __launch_bounds__(256)
void k_phase3(int g0, int g1,
              const short* oC, const short* woct, const float* boct,
              const short* wq_ca, const float* bq_ca,
              const short* wk_ca, const float* bk_ca,
              const short* wv_ca, const float* bv_ca,
              short* qC, unsigned* kvCa,
              const short* oT, const short* wotc, const float* botc, short* T2b,
              const short* U, const short* T1, const int* tind,
              const short* C1, const int* cind,
              const short* wen, const float* ben, short* Unew, const float* mkb,
              int BL, int L)
{
    __shared__ __align__(16) char smem[32768];
    int bx = blockIdx.x;
    if (bx < g0)
        octca_body(smem, bx, oC, woct, boct, wq_ca, bq_ca, wk_ca, bk_ca,
                   wv_ca, bv_ca, qC, kvCa, NB*NDV);
    else if (bx < g0+g1)
        mgemm_body<1,2>(smem, bx-g0, Seg{oT,nullptr,0}, Seg{nullptr,nullptr,0},
            Seg{nullptr,nullptr,0}, wotc, botc, T2b, NB*SS, 1, nullptr);
    else
        mgemm_body<3,3>(smem, bx-g0-g1, Seg{U,nullptr,0}, Seg{T1,tind,SS},
            Seg{C1,cind,NDV}, wen, ben, Unew, BL, L, mkb);
}

// Phase 4: fused ca attention + o-proj. One block per (b, qi) channel row.
__global__ __launch_bounds__(256)
void k_ca_fused(const short* __restrict__ qC, const unsigned* __restrict__ kv,
                const short* __restrict__ wo, const float* __restrict__ bo,
                short* __restrict__ C1)
{
    __shared__ __align__(16) short os[NKD];
    const int row = blockIdx.x;          // b*NDV + qi
    const int b = row / NDV;
    const int tid = threadIdx.x;
    const int h = tid >> 6;              // wave = head
    const int lane = tid & 63;
    const int d = lane & 31;
    const int half = lane >> 5;
    const float scale = 0.088388347648318447f;   // 1/sqrt(128)

    const float qv = bfs2f(qC[(size_t)row*NKD + h*DH + d]);
    const unsigned* kb = kv + (size_t)b*NDV*NKD + h*DH + d;

    float m = -INFINITY, ssum = 0.f, acc = 0.f;
    for (int l0 = 0; l0 < NDV; l0 += 2) {
        int l = l0 + half;
        unsigned ur = kb[(size_t)l*NKD];
        float kr = bf2f(ur & 0xffffu);
        float vr = bf2f(ur >> 16);
        float partial = qv * kr;
        #pragma unroll
        for (int off = 16; off; off >>= 1) partial += __shfl_xor(partial, off);
        float s = partial * scale;
        float mn = fmaxf(m, s);
        float corr = __expf(m - mn);
        float p = __expf(s - mn);
        ssum = ssum * corr + p;
        acc  = acc  * corr + p * vr;
        m = mn;
    }
    float mo = __shfl_xor(m, 32);
    float M = fmaxf(m, mo);
    float corr = (m > -1e30f) ? __expf(m - M) : 0.f;
    ssum *= corr; acc *= corr;
    ssum += __shfl_xor(ssum, 32);
    acc  += __shfl_xor(acc, 32);
    if (half == 0) {
        float res = (ssum > 0.f) ? acc / ssum : 0.f;
        os[h*DH + d] = f2bf(qv + res);
    }
    __syncthreads();

    const int n = tid >> 1;
    const int ks = (tid & 1) * 64;
    float a = 0.f;
    const short* wrow = wo + (size_t)n*NKD + ks;
    #pragma unroll
    for (int kk = 0; kk < 64; kk += 8) {
        short8 o8 = *(short8*)&os[ks + kk];
        short8 w8 = *(const short8*)(wrow + kk);
        #pragma unroll
        for (int j = 0; j < 8; j++) a += bfs2f(o8[j]) * bfs2f(w8[j]);
    }
    a += __shfl_xor(a, 1);
    if ((tid & 1) == 0) {
        float val = a + bo[n];
        val = bfs2f(os[n]) + fmaxf(val, 0.f);
        C1[(size_t)row*NKD + n] = f2bf(val);
    }
}

// Final head with inline gathers of k_t, k_c (bf16 inputs)
__global__ __launch_bounds__(256)
void k_out(const short* __restrict__ U, const short* __restrict__ T1,
           const short* __restrict__ C1, const int* __restrict__ tind,
           const int* __restrict__ cind, const float* __restrict__ ow,
           const float* __restrict__ obp, float* __restrict__ out,
           int BL, int L)
{
    int row = blockIdx.x * 4 + (threadIdx.x >> 6);
    int lane = threadIdx.x & 63;
    if (row >= BL) return;
    int b = row / L;
    int ti = tind[row]; if (ti < 0) ti = 0;
    int ci = cind[row]; if (ci < 0) ci = 0;
    const short* u = U + (size_t)row*NKD;
    const short* a = T1 + ((size_t)(b*SS + ti))*NKD;
    const short* c = C1 + ((size_t)(b*NDV + ci))*NKD;
    float s = bfs2f(u[lane])*ow[lane]     + bfs2f(u[lane+64])*ow[lane+64]
            + bfs2f(a[lane])*ow[128+lane] + bfs2f(a[lane+64])*ow[192+lane]
            + bfs2f(c[lane])*ow[256+lane] + bfs2f(c[lane+64])*ow[320+lane];
    #pragma unroll
    for (int off = 32; off; off >>= 1) s += __shfl_down(s, off);
    if (lane == 0) out[row] = s + obp[0];
}

// ---------------------------------------------------------------------------
extern "C" void kernel_launch(void* const* d_in, const int* in_sizes, int n_in,
                              void* d_out, int out_size, void* d_ws, size_t ws_size,
                              hipStream_t stream)
{
    const float* cx     = (const float*)d_in[0];
    const float* value  = (const float*)d_in[1];
    const float* maskp  = (const float*)d_in[2];
    const float* tval   = (const float*)d_in[3];
    const float* tmaskp = (const float*)d_in[4];
    const float* w0     = (const float*)d_in[5];
    const float* b0     = (const float*)d_in[6];
    const float* edge_w = (const float*)d_in[7];
    const float* edge_b = (const float*)d_in[8];
    const float* chan_w = (const float*)d_in[9];
    const float* chan_b = (const float*)d_in[10];
    const float* time_w = (const float*)d_in[11];
    const float* time_b = (const float*)d_in[12];
    const float* ct_wq = (const float*)d_in[13];
    const float* ct_bq = (const float*)d_in[14];
    const float* ct_wk = (const float*)d_in[15];
    const float* ct_bk = (const float*)d_in[16];
    const float* ct_wv = (const float*)d_in[17];
    const float* ct_bv = (const float*)d_in[18];
    const float* ct_wo = (const float*)d_in[19];
    const float* ct_bo = (const float*)d_in[20];
    const float* tc_wq = (const float*)d_in[21];
    const float* tc_bq = (const float*)d_in[22];
    const float* tc_wk = (const float*)d_in[23];
    const float* tc_bk = (const float*)d_in[24];
    const float* tc_wv = (const float*)d_in[25];
    const float* tc_bv = (const float*)d_in[26];
    const float* tc_wo = (const float*)d_in[27];
    const float* tc_bo = (const float*)d_in[28];
    const float* ca_wq = (const float*)d_in[29];
    const float* ca_bq = (const float*)d_in[30];
    const float* ca_wk = (const float*)d_in[31];
    const float* ca_bk = (const float*)d_in[32];
    const float* ca_wv = (const float*)d_in[33];
    const float* ca_bv = (const float*)d_in[34];
    const float* ca_wo = (const float*)d_in[35];
    const float* ca_bo = (const float*)d_in[36];
    const float* en_w  = (const float*)d_in[37];
    const float* en_b  = (const float*)d_in[38];
    const float* out_w = (const float*)d_in[39];
    const float* out_b = (const float*)d_in[40];

    const int BL = out_size / 3;     // B * full_len
    const int L  = BL / NB;

    char* p = (char*)d_ws;
    auto alloc = [&](size_t n) { char* r = p; p += (n + 255) & ~(size_t)255; return r; };
    int*      tind   = (int*)  alloc((size_t)BL*4);
    int*      cind   = (int*)  alloc((size_t)BL*4);
    float*    mkb    = (float*)alloc((size_t)BL*4);
    float*    uval   = (float*)alloc((size_t)BL*4);
    float*    uind   = (float*)alloc((size_t)BL*4);
    int*      lo_t   = (int*)  alloc((size_t)NB*SS*4);
    int*      hi_t   = (int*)  alloc((size_t)NB*SS*4);
    int*      clo    = (int*)  alloc((size_t)NB*NDV*4);
    int*      chi    = (int*)  alloc((size_t)NB*NDV*4);
    int*      invp   = (int*)  alloc((size_t)BL*4);
    short*    waren  = (short*)alloc((size_t)W_TOTAL*2);
    short*    U    = (short*)alloc((size_t)BL*NKD*2);
    short*    Unew = (short*)alloc((size_t)BL*NKD*2);
    unsigned* KVct = (unsigned*)alloc((size_t)BL*NKD*4);
    unsigned* KVtc = (unsigned*)alloc((size_t)BL*NKD*4);
    unsigned* kvCa = (unsigned*)alloc((size_t)NB*NDV*NKD*4);
    short*    T1   = (short*)alloc((size_t)NB*SS*NKD*2);
    short*    T2b  = (short*)alloc((size_t)NB*SS*NKD*2);
    short*    qT   = (short*)alloc((size_t)NB*SS*NKD*2);
    short*    oT   = (short*)alloc((size_t)NB*SS*NKD*2);
    short*    C1   = (short*)alloc((size_t)NB*NDV*NKD*2);
    short*    qC   = (short*)alloc((size_t)NB*NDV*NKD*2);
    short*    oC   = (short*)alloc((size_t)NB*NDV*NKD*2);

    float* outMain = (float*)d_out;
    float* outTU = outMain + BL;
    float* outTM = outMain + 2*BL;

    // weight arena offsets (shorts)
    const size_t OCTQ=0, OCTK=49152, OCTV=147456, OCTO=245760;
    const size_t OTCQ=294912, OTCK=344064, OTCV=442368, OTCO=540672;
    const size_t OCAQ=589824, OCAK=638976, OCAV=688128, OCAO=737280, OEN=786432;

    // Pre-phases (2 dispatches)
    k_pre_all<<<NB*NCH + 16 + 256 + 42 + W_TOTAL/256, 256, 0, stream>>>(
        cx, value, maskp, tval, tmaskp, w0, b0, L,
        tind, cind, mkb, uval, uind, outTU, outTM,
        lo_t, hi_t, time_w, time_b, T1, chan_w, chan_b, C1,
        ct_wq, ct_wk, ct_wv, ct_wo, tc_wq, tc_wk, tc_wv, tc_wo,
        ca_wq, ca_wk, ca_wv, ca_wo, en_w, waren);
    {
        const int gTr = (NB*L + 255)/256;
        const int gU  = (BL*16 + 255)/256;
        k_pre4<<<gTr + NB + gU, 256, 0, stream>>>(
            tind, lo_t, hi_t, L, gTr, cind, invp, clo, chi,
            uval, uind, mkb, edge_w, edge_b, U, BL);
    }

    const int gBL  = (BL + 127)/128;
    const int gKV  = (BL + 63)/64;       // M-tile 64 (R15's 32 regressed)
    const int gC   = (NB*NDV + 127)/128;
    const int gT   = (NB*SS + 127)/128;
    const int gCa  = (NB*NDV + 63)/64;
    const int aC2  = NB*NDV*NHD*2/4;     // SPLIT=2
    const int aTC  = NB*SS*NHD/4;        // SPLIT=1

    for (int i = 0; i < NLAY; i++) {
        const size_t bOff = (size_t)i*NKD;
        const short* wq_ct = waren + OCTQ + (size_t)i*128*128;
        const short* wk_ct = waren + OCTK + (size_t)i*256*128;
        const short* wv_ct = waren + OCTV + (size_t)i*256*128;
        const short* wo_ct = waren + OCTO + (size_t)i*128*128;
        const short* wq_tc = waren + OTCQ + (size_t)i*128*128;
        const short* wk_tc = waren + OTCK + (size_t)i*256*128;
        const short* wv_tc = waren + OTCV + (size_t)i*256*128;
        const short* wo_tc = waren + OTCO + (size_t)i*128*128;
        const short* wq_ca = waren + OCAQ + (size_t)i*128*128;
        const short* wk_ca = waren + OCAK + (size_t)i*128*128;
        const short* wv_ca = waren + OCAV + (size_t)i*128*128;
        const short* wo_ca = waren + OCAO + (size_t)i*128*128;
        const short* w_en  = waren + OEN  + (size_t)i*384*128;

        // P1: q/kv projections from (T1, C1, U)
        k_phase1<<<gKV + gC + gKV + gT, 256, 0, stream>>>(
            gKV, gC, gKV,
            T1, tind, U,
            wk_ct, ct_bk + bOff, wv_ct, ct_bv + bOff, KVct, invp,
            C1, wq_ct, ct_bq + bOff, qC,
            cind, wk_tc, tc_bk + bOff, wv_tc, tc_bv + bOff, KVtc,
            wq_tc, tc_bq + bOff, qT, BL, L);
        // P2: both segmented attentions
        k_phase2<<<aC2 + aTC, 256, 0, stream>>>(
            aC2, qC, KVct, oC, clo, chi, L, qT, KVtc, oT, lo_t, hi_t);
        // P3: fused ct-o-proj+ca-kvq | o-tc | en
        k_phase3<<<gCa + gT + gBL, 256, 0, stream>>>(
            gCa, gT,
            oC, wo_ct, ct_bo + bOff,
            wq_ca, ca_bq + bOff, wk_ca, ca_bk + bOff, wv_ca, ca_bv + bOff,
            qC, kvCa,
            oT, wo_tc, tc_bo + bOff, T2b,
            U, T1, tind, C1, cind, w_en, en_b + bOff, Unew, mkb, BL, L);
        // P4: fused ca attention + o-proj (672 blocks — stays parallel)
        k_ca_fused<<<NB*NDV, 256, 0, stream>>>(qC, kvCa, wo_ca, ca_bo + bOff, C1);

        short* t = U;  U = Unew; Unew = t;
        t = T1; T1 = T2b; T2b = t;
    }

    k_out<<<(BL + 3)/4, 256, 0, stream>>>(U, T1, C1, tind, cind,
                                          out_w, out_b, outMain, BL, L);
}

// Round 17
// 434.483 us; speedup vs baseline: 1.0522x; 1.0204x over previous
//
#include <hip/hip_runtime.h>
#include <math.h>

#define NB   16
#define SS   256
#define DIMV 41
#define NDV  42
#define NKD  128
#define NHD  4
#define DH   32
#define NLAY 3
#define TOT  (SS*NDV)   // 10752 = 42 chunks of 256
#define NCH  42

typedef __attribute__((ext_vector_type(8))) short short8;
typedef __attribute__((ext_vector_type(4))) float floatx4;

__device__ __forceinline__ short f2bf(float x) {
    unsigned u = __float_as_uint(x);
    u += 0x7fff + ((u >> 16) & 1);          // RNE f32 -> bf16
    return (short)(u >> 16);
}
__device__ __forceinline__ float bfs2f(short s) {
    return __uint_as_float(((unsigned)(unsigned short)s) << 16);
}
__device__ __forceinline__ float bf2f(unsigned s) {
    return __uint_as_float(s << 16);
}

struct Seg { const short* ptr; const int* ind; int ns; };

__device__ __forceinline__ const short* seg_row(const Seg s, int gm, int Lb) {
    if (s.ind) {
        int b = gm / Lb;
        int id = s.ind[gm]; if (id < 0) id = 0;
        return s.ptr + ((size_t)b * s.ns + (size_t)id) * NKD;
    }
    return s.ptr + (size_t)gm * NKD;
}

// ===========================================================================
// Device bodies
// ===========================================================================

__device__ __forceinline__ void compactA_body(int bx, const float* __restrict__ maskp,
                                              int* __restrict__ chunkcnt)
{
    const int b = bx / NCH, ch = bx % NCH;
    const int tid = threadIdx.x;
    const int idx = ch * 256 + tid;
    const int s = idx / NDV, c = idx % NDV;
    float m = (c < DIMV) ? maskp[((size_t)b*SS + s)*DIMV + c] : 1.0f;
    int x = (m != 0.0f) ? 1 : 0;
    #pragma unroll
    for (int off = 32; off; off >>= 1) x += __shfl_down(x, off);
    __shared__ int ws4[4];
    if ((tid & 63) == 0) ws4[tid >> 6] = x;
    __syncthreads();
    if (tid == 0) chunkcnt[bx] = ws4[0] + ws4[1] + ws4[2] + ws4[3];
}

__device__ __forceinline__ void zero_body(int bx, int* __restrict__ lo_t,
                                          int* __restrict__ hi_t)
{
    int i = bx*256 + threadIdx.x;
    if (i < NB*SS) { lo_t[i] = 0; hi_t[i] = 0; }
}

__device__ __forceinline__ void initT_body(int bx, const float* __restrict__ cx,
                                           const float* __restrict__ tw,
                                           const float* __restrict__ tb,
                                           short* __restrict__ T)
{
    int i = bx * 256 + threadIdx.x;
    if (i >= NB*SS*16) return;
    int row = i >> 4;
    int k = (i & 15) << 3;
    float t = cx[row];
    short8 r;
    #pragma unroll
    for (int j = 0; j < 8; j++) r[j] = f2bf(sinf(t*tw[k+j] + tb[k+j]));
    *(short8*)(T + (size_t)row*NKD + k) = r;
}

__device__ __forceinline__ void initC_body(int bx, const float* __restrict__ cw,
                                           const float* __restrict__ cb,
                                           short* __restrict__ C)
{
    int i = bx * 256 + threadIdx.x;
    if (i >= NB*NDV*16) return;
    int row = i >> 4;
    int c = row % NDV;
    int k = (i & 15) << 3;
    short8 r;
    #pragma unroll
    for (int j = 0; j < 8; j++) r[j] = f2bf(fmaxf(cw[(size_t)c*NKD + k+j] + cb[k+j], 0.f));
    *(short8*)(C + (size_t)row*NKD + k) = r;
}

template<int Kg>
__device__ __forceinline__ void prep1(const float* __restrict__ src,
                                      short* __restrict__ dst, int rel)
{
    const int per = Kg*128;
    int i = rel / per; int r2 = rel - i*per;
    int n = r2 / Kg;   int k = r2 - n*Kg;
    dst[rel] = f2bf(src[(size_t)i*per + (size_t)k*128 + n]);
}

#define W_TOTAL 933888
__device__ __forceinline__ void prepw_body(int bx,
    const float* ctq, const float* ctk, const float* ctv, const float* cto,
    const float* tcq, const float* tck, const float* tcv, const float* tco,
    const float* caq, const float* cak, const float* cav, const float* cao,
    const float* enw, short* __restrict__ arena)
{
    int idx = bx*256 + threadIdx.x;
    if (idx >= W_TOTAL) return;
    if      (idx < 49152 ) prep1<128>(ctq, arena + 0,      idx - 0);
    else if (idx < 147456) prep1<256>(ctk, arena + 49152,  idx - 49152);
    else if (idx < 245760) prep1<256>(ctv, arena + 147456, idx - 147456);
    else if (idx < 294912) prep1<128>(cto, arena + 245760, idx - 245760);
    else if (idx < 344064) prep1<128>(tcq, arena + 294912, idx - 294912);
    else if (idx < 442368) prep1<256>(tck, arena + 344064, idx - 344064);
    else if (idx < 540672) prep1<256>(tcv, arena + 442368, idx - 442368);
    else if (idx < 589824) prep1<128>(tco, arena + 540672, idx - 540672);
    else if (idx < 638976) prep1<128>(caq, arena + 589824, idx - 589824);
    else if (idx < 688128) prep1<128>(cak, arena + 638976, idx - 638976);
    else if (idx < 737280) prep1<128>(cav, arena + 688128, idx - 688128);
    else if (idx < 786432) prep1<128>(cao, arena + 737280, idx - 737280);
    else                   prep1<384>(enw, arena + 786432, idx - 786432);
}

__device__ __forceinline__ void trange_body(int bx, const int* __restrict__ tind,
                                            int* __restrict__ lo_t,
                                            int* __restrict__ hi_t, int L)
{
    int p = bx*256 + threadIdx.x;
    if (p >= NB*L) return;
    int b = p / L, l = p - b*L;
    int t = tind[p];
    if (t < 0) return;
    int tp = (l > 0) ? tind[p-1] : -999;
    int tn = (l+1 < L) ? tind[p+1] : -999;
    if (tp != t) lo_t[b*SS + t] = l;
    if (tn != t) hi_t[b*SS + t] = l+1;
}

__device__ __forceinline__ void cperm_body(int b, const int* __restrict__ cind,
                                           int* __restrict__ invp,
                                           int* __restrict__ clo,
                                           int* __restrict__ chi, int L)
{
    __shared__ int hist[NDV];
    __shared__ int base[NDV];
    __shared__ int padc, cntsh;
    const int tid = threadIdx.x;
    if (tid < NDV) hist[tid] = 0;
    if (tid == 0) padc = 0;
    __syncthreads();
    for (int l = tid; l < L; l += 256) {
        int c = cind[(size_t)b*L + l];
        if (c >= 0) atomicAdd(&hist[c], 1);
    }
    __syncthreads();
    if (tid == 0) {
        int run = 0;
        for (int c = 0; c < NDV; c++) {
            base[c] = run; clo[b*NDV + c] = run;
            run += hist[c]; chi[b*NDV + c] = run;
        }
        cntsh = run;
    }
    __syncthreads();
    if (tid < NDV) hist[tid] = 0;
    __syncthreads();
    const int cnt = cntsh;
    for (int l = tid; l < L; l += 256) {
        int c = cind[(size_t)b*L + l];
        int pos;
        if (c >= 0) pos = base[c] + atomicAdd(&hist[c], 1);
        else        pos = cnt + atomicAdd(&padc, 1);
        invp[(size_t)b*L + l] = b*L + pos;
    }
}

__device__ __forceinline__ void initU_body(int bx, const float* __restrict__ uval,
                                           const float* __restrict__ uind,
                                           const float* __restrict__ mkb,
                                           const float* __restrict__ ew,
                                           const float* __restrict__ eb,
                                           short* __restrict__ U, int BL)
{
    int i = bx * 256 + threadIdx.x;
    if (i >= BL*16) return;
    int row = i >> 4;
    int k = (i & 15) << 3;
    float uv = uval[row], ui = uind[row], m = mkb[row];
    short8 r;
    #pragma unroll
    for (int j = 0; j < 8; j++)
        r[j] = f2bf(fmaxf(uv*ew[k+j] + ui*ew[NKD+k+j] + eb[k+j], 0.f) * m);
    *(short8*)(U + (size_t)row*NKD + k) = r;
}

// ---------------------------------------------------------------------------
// MFMA GEMM body (M-tile 128), bf16 activations in/out. smem >= 20480
// MODE 0: D = acc+b ; MODE 2: D = A0 + relu(acc+b) ; MODE 3: relu(A0+acc+b)*mk
// ---------------------------------------------------------------------------
template<int NSEG, int MODE>
__device__ __forceinline__ void mgemm_body(char* smem, int bx,
           Seg s0, Seg s1, Seg s2, const short* __restrict__ Wt,
           const float* __restrict__ bias, short* __restrict__ D,
           int M, int Lb, const float* __restrict__ mkp)
{
    short (*As)[40] = (short (*)[40])smem;
    short (*Bs)[40] = (short (*)[40])(smem + 10240);
    const int bm = bx * 128;
    const int tid = threadIdx.x;
    const int wv = tid >> 6;
    const int lane = tid & 63;
    const int quad = lane >> 4;
    const int l16 = lane & 15;
    const int K = NSEG * 128;
    floatx4 acc[2][8];
    #pragma unroll
    for (int i = 0; i < 2; i++)
        #pragma unroll
        for (int j = 0; j < 8; j++) acc[i][j] = (floatx4){0.f,0.f,0.f,0.f};

    const int arow = tid >> 1;
    const int acol = (tid & 1) * 16;
    int gmc = bm + arow; if (gmc > M-1) gmc = M-1;
    const short* rowp0 = seg_row(s0, gmc, Lb);
    const short* rowp1 = (NSEG > 1) ? seg_row(s1, gmc, Lb) : nullptr;
    const short* rowp2 = (NSEG > 2) ? seg_row(s2, gmc, Lb) : nullptr;

    for (int k0 = 0; k0 < K; k0 += 32) {
        {
            const short* rp;
            if (NSEG == 1) rp = rowp0;
            else if (NSEG == 2) rp = (k0 < 128) ? rowp0 : rowp1;
            else rp = (k0 < 128) ? rowp0 : ((k0 < 256) ? rowp1 : rowp2);
            const int ks = k0 & 127;
            const short* src = rp + ks + acol;
            *(short8*)&As[arow][acol]   = *(const short8*)(src);
            *(short8*)&As[arow][acol+8] = *(const short8*)(src+8);
        }
        {
            const short* src = Wt + (size_t)arow*K + k0 + acol;
            *(short8*)&Bs[arow][acol]   = *(const short8*)(src);
            *(short8*)&Bs[arow][acol+8] = *(const short8*)(src+8);
        }
        __syncthreads();
        short8 af0 = *(short8*)&As[wv*32 + l16][quad*8];
        short8 af1 = *(short8*)&As[wv*32 + 16 + l16][quad*8];
        #pragma unroll
        for (int nf = 0; nf < 8; nf++) {
            short8 bf = *(short8*)&Bs[nf*16 + l16][quad*8];
            acc[0][nf] = __builtin_amdgcn_mfma_f32_16x16x32_bf16(af0, bf, acc[0][nf], 0, 0, 0);
            acc[1][nf] = __builtin_amdgcn_mfma_f32_16x16x32_bf16(af1, bf, acc[1][nf], 0, 0, 0);
        }
        __syncthreads();
    }
    #pragma unroll
    for (int mf = 0; mf < 2; mf++) {
        #pragma unroll
        for (int r = 0; r < 4; r++) {
            int gm = bm + wv*32 + mf*16 + quad*4 + r;
            if (gm < M) {
                float mk = (MODE == 3) ? mkp[gm] : 0.f;
                const short* res = (MODE == 2 || MODE == 3) ? seg_row(s0, gm, Lb) : nullptr;
                #pragma unroll
                for (int nf = 0; nf < 8; nf++) {
                    int gn = nf*16 + l16;
                    float val = acc[mf][nf][r] + bias[gn];
                    if (MODE == 2) val = bfs2f(res[gn]) + fmaxf(val, 0.f);
                    else if (MODE == 3) val = fmaxf(bfs2f(res[gn]) + val, 0.f) * mk;
                    D[(size_t)gm*NKD + gn] = f2bf(val);
                }
            }
        }
    }
}

// ---------------------------------------------------------------------------
// Dual-output KV GEMM body (M-tile 64): packed bf16 (k | v<<16). smem >= 25600
// ---------------------------------------------------------------------------
template<int NSEG>
__device__ __forceinline__ void mgemm_kv_body(char* smem, int bx,
              Seg s0, Seg s1,
              const short* __restrict__ Wk, const float* __restrict__ bk,
              const short* __restrict__ Wv, const float* __restrict__ bv,
              unsigned* __restrict__ KV, int M, int Lb, const int* __restrict__ rmap)
{
    short (*As)[40] = (short (*)[40])smem;
    short (*Bk_)[40] = (short (*)[40])(smem + 5120);
    short (*Bv_)[40] = (short (*)[40])(smem + 15360);
    const int bm = bx * 64;
    const int tid = threadIdx.x;
    const int wv = tid >> 6;
    const int lane = tid & 63;
    const int quad = lane >> 4;
    const int l16 = lane & 15;
    const int K = NSEG * 128;
    floatx4 acck[8], accv[8];
    #pragma unroll
    for (int j = 0; j < 8; j++) {
        acck[j] = (floatx4){0.f,0.f,0.f,0.f};
        accv[j] = (floatx4){0.f,0.f,0.f,0.f};
    }

    const int arow = tid >> 2;
    const int acol = (tid & 3) * 8;
    const int brow = tid >> 1;
    const int bcol = (tid & 1) * 16;
    int gmc = bm + arow; if (gmc > M-1) gmc = M-1;
    const short* rowp0 = seg_row(s0, gmc, Lb);
    const short* rowp1 = (NSEG > 1) ? seg_row(s1, gmc, Lb) : nullptr;

    for (int k0 = 0; k0 < K; k0 += 32) {
        {
            const short* rp = (NSEG == 1) ? rowp0 : ((k0 < 128) ? rowp0 : rowp1);
            const int ks = k0 & 127;
            *(short8*)&As[arow][acol] = *(const short8*)(rp + ks + acol);
        }
        {
            const short* sk = Wk + (size_t)brow*K + k0 + bcol;
            *(short8*)&Bk_[brow][bcol]   = *(const short8*)(sk);
            *(short8*)&Bk_[brow][bcol+8] = *(const short8*)(sk+8);
            const short* sv = Wv + (size_t)brow*K + k0 + bcol;
            *(short8*)&Bv_[brow][bcol]   = *(const short8*)(sv);
            *(short8*)&Bv_[brow][bcol+8] = *(const short8*)(sv+8);
        }
        __syncthreads();
        short8 af = *(short8*)&As[wv*16 + l16][quad*8];
        #pragma unroll
        for (int nf = 0; nf < 8; nf++) {
            short8 bfk = *(short8*)&Bk_[nf*16 + l16][quad*8];
            acck[nf] = __builtin_amdgcn_mfma_f32_16x16x32_bf16(af, bfk, acck[nf], 0, 0, 0);
            short8 bfv = *(short8*)&Bv_[nf*16 + l16][quad*8];
            accv[nf] = __builtin_amdgcn_mfma_f32_16x16x32_bf16(af, bfv, accv[nf], 0, 0, 0);
        }
        __syncthreads();
    }
    #pragma unroll
    for (int r = 0; r < 4; r++) {
        int gm = bm + wv*16 + quad*4 + r;
        if (gm < M) {
            int orow = rmap ? rmap[gm] : gm;
            #pragma unroll
            for (int nf = 0; nf < 8; nf++) {
                int gn = nf*16 + l16;
                float kf = acck[nf][r] + bk[gn];
                float vf = accv[nf][r] + bv[gn];
                unsigned pk = (unsigned)(unsigned short)f2bf(kf)
                            | ((unsigned)(unsigned short)f2bf(vf) << 16);
                KV[(size_t)orow*NKD + gn] = pk;
            }
        }
    }
}

// ---------------------------------------------------------------------------
// Fused ct-o-proj + ca q/k/v (M-tile 64): C2 = oC + relu(oC@wo+bo) lives only
// in LDS; q -> qC (bf16), k/v -> packed kvCa. smem >= 32768.
// ---------------------------------------------------------------------------
__device__ __forceinline__ void octca_body(char* smem, int bx,
    const short* __restrict__ oC,
    const short* __restrict__ wo, const float* __restrict__ bo,
    const short* __restrict__ wq, const float* __restrict__ bq,
    const short* __restrict__ wk, const float* __restrict__ bk,
    const short* __restrict__ wv, const float* __restrict__ bv,
    short* __restrict__ qC, unsigned* __restrict__ KV, int M)
{
    short (*C2t)[136] = (short (*)[136])smem;            // 17408 B
    short (*Bs)[40]   = (short (*)[40])(smem + 17408);   // 10240 B
    short (*As)[40]   = (short (*)[40])(smem + 27648);   // 5120 B
    const int bm = bx * 64;
    const int tid = threadIdx.x;
    const int wv_ = tid >> 6;
    const int lane = tid & 63;
    const int quad = lane >> 4;
    const int l16 = lane & 15;
    const int arow = tid >> 2;
    const int acol = (tid & 3) * 8;
    const int brow = tid >> 1;
    const int bcol = (tid & 1) * 16;
    int gmc = bm + arow; if (gmc > M-1) gmc = M-1;
    const short* rowp = oC + (size_t)gmc * NKD;

    floatx4 acc[8];
    #pragma unroll
    for (int j = 0; j < 8; j++) acc[j] = (floatx4){0.f,0.f,0.f,0.f};
    for (int k0 = 0; k0 < 128; k0 += 32) {
        *(short8*)&As[arow][acol] = *(const short8*)(rowp + k0 + acol);
        const short* sw = wo + (size_t)brow*128 + k0 + bcol;
        *(short8*)&Bs[brow][bcol]   = *(const short8*)(sw);
        *(short8*)&Bs[brow][bcol+8] = *(const short8*)(sw+8);
        __syncthreads();
        short8 af = *(short8*)&As[wv_*16 + l16][quad*8];
        #pragma unroll
        for (int nf = 0; nf < 8; nf++) {
            short8 bf = *(short8*)&Bs[nf*16 + l16][quad*8];
            acc[nf] = __builtin_amdgcn_mfma_f32_16x16x32_bf16(af, bf, acc[nf], 0, 0, 0);
        }
        __syncthreads();
    }
    #pragma unroll
    for (int r = 0; r < 4; r++) {
        int lrow = wv_*16 + quad*4 + r;
        int gm = bm + lrow; int gmr = (gm > M-1) ? (M-1) : gm;
        const short* res = oC + (size_t)gmr*NKD;
        #pragma unroll
        for (int nf = 0; nf < 8; nf++) {
            int gn = nf*16 + l16;
            float val = acc[nf][r] + bo[gn];
            val = bfs2f(res[gn]) + fmaxf(val, 0.f);
            C2t[lrow][gn] = f2bf(val);
        }
    }
    __syncthreads();

    floatx4 acck[8];
    for (int proj = 0; proj < 3; proj++) {
        const short* W = (proj == 0) ? wq : ((proj == 1) ? wk : wv);
        floatx4 a2[8];
        #pragma unroll
        for (int j = 0; j < 8; j++) a2[j] = (floatx4){0.f,0.f,0.f,0.f};
        for (int k0 = 0; k0 < 128; k0 += 32) {
            const short* sw = W + (size_t)brow*128 + k0 + bcol;
            *(short8*)&Bs[brow][bcol]   = *(const short8*)(sw);
            *(short8*)&Bs[brow][bcol+8] = *(const short8*)(sw+8);
            __syncthreads();
            short8 af = *(short8*)&C2t[wv_*16 + l16][k0 + quad*8];
            #pragma unroll
            for (int nf = 0; nf < 8; nf++) {
                short8 bf = *(short8*)&Bs[nf*16 + l16][quad*8];
                a2[nf] = __builtin_amdgcn_mfma_f32_16x16x32_bf16(af, bf, a2[nf], 0, 0, 0);
            }
            __syncthreads();
        }
        if (proj == 0) {
            #pragma unroll
            for (int r = 0; r < 4; r++) {
                int gm = bm + wv_*16 + quad*4 + r;
                if (gm < M) {
                    #pragma unroll
                    for (int nf = 0; nf < 8; nf++) {
                        int gn = nf*16 + l16;
                        qC[(size_t)gm*NKD + gn] = f2bf(a2[nf][r] + bq[gn]);
                    }
                }
            }
        } else if (proj == 1) {
            #pragma unroll
            for (int j = 0; j < 8; j++) acck[j] = a2[j];
        } else {
            #pragma unroll
            for (int r = 0; r < 4; r++) {
                int gm = bm + wv_*16 + quad*4 + r;
                if (gm < M) {
                    #pragma unroll
                    for (int nf = 0; nf < 8; nf++) {
                        int gn = nf*16 + l16;
                        float kf = acck[nf][r] + bk[gn];
                        float vf = a2[nf][r] + bv[gn];
                        KV[(size_t)gm*NKD + gn] =
                            (unsigned)(unsigned short)f2bf(kf)
                          | ((unsigned)(unsigned short)f2bf(vf) << 16);
                    }
                }
            }
        }
    }
}

// ---------------------------------------------------------------------------
// Segmented attention body on packed bf16 KV, bf16 q/o. SPLIT waves/(b,q,h).
// ---------------------------------------------------------------------------
template<int SPLIT>
__device__ __forceinline__ void sattn_body(int bx,
                  const short* __restrict__ q, const unsigned* __restrict__ kvb,
                  short* __restrict__ o, int nq, int nkv,
                  const int* __restrict__ lo_arr, const int* __restrict__ hi_arr)
{
    __shared__ float sm_m[4], sm_s[4], sm_a[4][DH];
    const int wvid = threadIdx.x >> 6;
    int gtask = bx * 4 + wvid;
    int task = gtask / SPLIT;
    int part = gtask % SPLIT;
    if (task >= NB * nq * NHD) return;
    const int h = task & 3;
    const int bq = task >> 2;
    const int qi = bq % nq;
    const int b = bq / nq;
    const int lane = threadIdx.x & 63;
    const int d = lane & 31;
    const int half = lane >> 5;
    int lo = lo_arr ? lo_arr[b*nq + qi] : 0;
    int hi = hi_arr ? hi_arr[b*nq + qi] : nkv;
    if (SPLIT == 2) {
        int mid = lo + ((hi - lo + 1) >> 1);
        if (part == 0) hi = mid; else lo = mid;
    }
    const float scale = 0.088388347648318447f;   // 1/sqrt(128)

    const float qv = bfs2f(q[((size_t)(b*nq + qi))*NKD + h*DH + d]);
    const unsigned* kb = kvb + (size_t)b*nkv*NKD + h*DH + d;

    float m = -INFINITY, ssum = 0.f, acc = 0.f;
    for (int l0 = lo; l0 < hi; l0 += 8) {
        unsigned ur[4];
        #pragma unroll
        for (int j = 0; j < 4; j++) {
            int l = l0 + 2*j + half;
            bool ok = (l < hi);
            ur[j] = ok ? kb[(size_t)l*NKD] : 0u;
        }
        #pragma unroll
        for (int j = 0; j < 4; j++) {
            int l = l0 + 2*j + half;
            float kr = bf2f(ur[j] & 0xffffu);
            float vr = bf2f(ur[j] >> 16);
            float partial = qv * kr;
            #pragma unroll
            for (int off = 16; off; off >>= 1) partial += __shfl_xor(partial, off);
            float s = partial * scale;
            if (l < hi) {
                float mn = fmaxf(m, s);
                float corr = __expf(m - mn);
                float p = __expf(s - mn);
                ssum = ssum * corr + p;
                acc  = acc  * corr + p * vr;
                m = mn;
            }
        }
    }
    float mo = __shfl_xor(m, 32);
    float M = fmaxf(m, mo);
    float corr = (m > -1e30f) ? __expf(m - M) : 0.f;
    ssum *= corr; acc *= corr;
    ssum += __shfl_xor(ssum, 32);
    acc  += __shfl_xor(acc, 32);

    if (SPLIT == 1) {
        if (half == 0) {
            float res = (ssum > 0.f) ? acc / ssum : 0.f;
            o[((size_t)(b*nq + qi))*NKD + h*DH + d] = f2bf(qv + res);
        }
    } else {
        if (lane == 0) { sm_m[wvid] = M; sm_s[wvid] = ssum; }
        if (lane < DH) sm_a[wvid][lane] = acc;
        __syncthreads();
        if (part == 0 && lane < DH) {
            float m2 = sm_m[wvid+1], s2 = sm_s[wvid+1], a2 = sm_a[wvid+1][lane];
            float M2 = fmaxf(M, m2);
            float c1 = (M  > -1e30f) ? __expf(M  - M2) : 0.f;
            float c2 = (m2 > -1e30f) ? __expf(m2 - M2) : 0.f;
            float S = ssum * c1 + s2 * c2;
            float A = acc  * c1 + a2 * c2;
            float res = (S > 0.f) ? A / S : 0.f;
            float qv2 = bfs2f(q[((size_t)(b*nq + qi))*NKD + h*DH + lane]);
            o[((size_t)(b*nq + qi))*NKD + h*DH + lane] = f2bf(qv2 + res);
        }
    }
}

// ===========================================================================
// Kernels
// ===========================================================================

// Pre-phase 1: compactA + zero_ranges + initT + initC + prep_weights
__global__ __launch_bounds__(256)
void k_pre1(const float* maskp, int* chunkcnt, int* lo_t, int* hi_t,
            const float* cx, const float* tw, const float* tb, short* T,
            const float* cw, const float* cb, short* C,
            const float* ctq, const float* ctk, const float* ctv, const float* cto,
            const float* tcq, const float* tck, const float* tcv, const float* tco,
            const float* caq, const float* cak, const float* cav, const float* cao,
            const float* enw, short* arena)
{
    int bx = blockIdx.x;
    if (bx < NB*NCH)            compactA_body(bx, maskp, chunkcnt);
    else if (bx < NB*NCH + 16)  zero_body(bx - NB*NCH, lo_t, hi_t);
    else if (bx < NB*NCH + 16 + 256) initT_body(bx - NB*NCH - 16, cx, tw, tb, T);
    else if (bx < NB*NCH + 16 + 256 + 42) initC_body(bx - NB*NCH - 16 - 256, cw, cb, C);
    else prepw_body(bx - NB*NCH - 16 - 256 - 42,
                    ctq, ctk, ctv, cto, tcq, tck, tcv, tco,
                    caq, cak, cav, cao, enw, arena);
}

// compactC with in-block scan of chunk counts (compactB folded in)
__global__ __launch_bounds__(256)
void k_compactC(const float* __restrict__ cx, const float* __restrict__ value,
              const float* __restrict__ maskp, const float* __restrict__ tval,
              const float* __restrict__ tmaskp, const float* __restrict__ w0p,
              const float* __restrict__ b0p,
              const int* __restrict__ chunkcnt, int L,
              int* __restrict__ tind, int* __restrict__ cind,
              float* __restrict__ mkb, float* __restrict__ uval,
              float* __restrict__ uind,
              float* __restrict__ outTU, float* __restrict__ outTM)
{
    const int blk = blockIdx.x;
    const int b = blk / NCH, ch = blk % NCH;
    const int tid = threadIdx.x, lane = tid & 63, wv = tid >> 6;
    const int idx = ch * 256 + tid;
    const int s = idx / NDV, c = idx % NDV;
    float mval = (c < DIMV) ? maskp[((size_t)b*SS + s)*DIMV + c] : 1.0f;
    int m = (mval != 0.0f) ? 1 : 0;
    int x = m;
    #pragma unroll
    for (int off = 1; off < 64; off <<= 1) {
        int y = __shfl_up(x, off);
        if (lane >= off) x += y;
    }
    __shared__ int wsum[4];
    __shared__ int s_off, s_cnt;
    if (lane == 63) wsum[wv] = x;
    if (tid < 64) {
        int v2 = (tid < NCH) ? chunkcnt[b*NCH + tid] : 0;
        int x2 = v2;
        #pragma unroll
        for (int off = 1; off < 64; off <<= 1) {
            int y2 = __shfl_up(x2, off);
            if (tid >= off) x2 += y2;
        }
        if (tid == ch) s_off = x2 - v2;
        if (tid == 63) s_cnt = x2;
    }
    __syncthreads();
    int wbase = 0;
    for (int w = 0; w < wv; w++) wbase += wsum[w];
    const int excl = x - m + wbase;
    const int vbefore = s_off + excl;
    const int cnt = s_cnt;
    const int pos = m ? vbefore : (cnt + (idx - vbefore));
    if (pos < L) {
        const float w0 = w0p[0], b0 = b0p[0];
        float te = w0 * cx[(size_t)b*SS + s] + b0;
        float vf, tvf, tmf;
        if (c < DIMV) {
            size_t o = ((size_t)b*SS + s)*DIMV + c;
            vf = value[o]; tvf = tval[o]; tmf = tmaskp[o];
        } else { vf = te; tvf = te; tmf = 0.0f; }
        size_t p = (size_t)b*L + pos;
        if (m) {
            tind[p] = s; cind[p] = c; mkb[p] = 1.0f;
            uval[p] = vf; uind[p] = tmf;
            outTU[p] = tvf; outTM[p] = tmf;
        } else {
            tind[p] = -1; cind[p] = -1; mkb[p] = 0.0f;
            uval[p] = 0.0f; uind[p] = 1.0f;
            outTU[p] = 0.0f; outTM[p] = 0.0f;
        }
    }
}

// Pre-phase 4: trange + cperm + initU
__global__ __launch_bounds__(256)
void k_pre4(const int* tind, int* lo_t, int* hi_t, int L, int gTr,
            const int* cind, int* invp, int* clo, int* chi,
            const float* uval, const float* uind, const float* mkb,
            const float* ew, const float* eb, short* U, int BL)
{
    int bx = blockIdx.x;
    if (bx < gTr) trange_body(bx, tind, lo_t, hi_t, L);
    else if (bx < gTr + NB) cperm_body(bx - gTr, cind, invp, clo, chi, L);
    else initU_body(bx - gTr - NB, uval, uind, mkb, ew, eb, U, BL);
}

// Phase 1: ct-kv + ct-q + tc-kv + tc-q
__global__ __launch_bounds__(256)
void k_phase1(int g0, int g1, int g2,
              const short* T1, const int* tind, const short* U,
              const short* wkct, const float* bkct, const short* wvct, const float* bvct,
              unsigned* KVct, const int* invp,
              const short* C1, const short* wqct, const float* bqct, short* qC,
              const int* cind,
              const short* wktc, const float* bktc, const short* wvtc, const float* bvtc,
              unsigned* KVtc,
              const short* wqtc, const float* bqtc, short* qT,
              int BL, int L)
{
    __shared__ __align__(16) char smem[25600];
    int bx = blockIdx.x;
    if (bx < g0) {
        mgemm_kv_body<2>(smem, bx, Seg{T1,tind,SS}, Seg{U,nullptr,0},
            wkct, bkct, wvct, bvct, KVct, BL, L, invp);
    } else if (bx < g0+g1) {
        mgemm_body<1,0>(smem, bx-g0, Seg{C1,nullptr,0}, Seg{nullptr,nullptr,0},
            Seg{nullptr,nullptr,0}, wqct, bqct, qC, NB*NDV, 1, nullptr);
    } else if (bx < g0+g1+g2) {
        mgemm_kv_body<2>(smem, bx-g0-g1, Seg{C1,cind,NDV}, Seg{U,nullptr,0},
            wktc, bktc, wvtc, bvtc, KVtc, BL, L, nullptr);
    } else {
        mgemm_body<1,0>(smem, bx-g0-g1-g2, Seg{T1,nullptr,0}, Seg{nullptr,nullptr,0},
            Seg{nullptr,nullptr,0}, wqtc, bqtc, qT, NB*SS, 1, nullptr);
    }
}

// Phase 2: sattn ct + sattn tc
__global__ __launch_bounds__(256)
void k_phase2(int g0, const short* qC, const unsigned* KVct, short* oC,
              const int* clo, const int* chi, int L,
              const short* qT, const unsigned* KVtc, short* oT,
              const int* lo_t, const int* hi_t)
{
    int bx = blockIdx.x;
    if (bx < g0) sattn_body<2>(bx, qC, KVct, oC, NDV, L, clo, chi);
    else         sattn_body<1>(bx-g0, qT, KVtc, oT, SS, L, lo_t, hi_t);
}

// Phase 3: fused ct-o-proj + ca q/k/v | o-tc -> T2b | en -> Unew
__global__ __launch_bounds__(256)
void k_phase3(int g0, int g1,
              const short* oC, const short* woct, const float* boct,
              const short* wq_ca, const float* bq_ca,
              const short* wk_ca, const float* bk_ca,
              const short* wv_ca, const float* bv_ca,
              short* qC, unsigned* kvCa,
              const short* oT, const short* wotc, const float* botc, short* T2b,
              const short* U, const short* T1, const int* tind,
              const short* C1, const int* cind,
              const short* wen, const float* ben, short* Unew, const float* mkb,
              int BL, int L)
{
    __shared__ __align__(16) char smem[32768];
    int bx = blockIdx.x;
    if (bx < g0)
        octca_body(smem, bx, oC, woct, boct, wq_ca, bq_ca, wk_ca, bk_ca,
                   wv_ca, bv_ca, qC, kvCa, NB*NDV);
    else if (bx < g0+g1)
        mgemm_body<1,2>(smem, bx-g0, Seg{oT,nullptr,0}, Seg{nullptr,nullptr,0},
            Seg{nullptr,nullptr,0}, wotc, botc, T2b, NB*SS, 1, nullptr);
    else
        mgemm_body<3,3>(smem, bx-g0-g1, Seg{U,nullptr,0}, Seg{T1,tind,SS},
            Seg{C1,cind,NDV}, wen, ben, Unew, BL, L, mkb);
}

// Phase 4: fused ca attention + o-proj. One block per (b, qi) channel row.
__global__ __launch_bounds__(256)
void k_ca_fused(const short* __restrict__ qC, const unsigned* __restrict__ kv,
                const short* __restrict__ wo, const float* __restrict__ bo,
                short* __restrict__ C1)
{
    __shared__ __align__(16) short os[NKD];
    const int row = blockIdx.x;          // b*NDV + qi
    const int b = row / NDV;
    const int tid = threadIdx.x;
    const int h = tid >> 6;              // wave = head
    const int lane = tid & 63;
    const int d = lane & 31;
    const int half = lane >> 5;
    const float scale = 0.088388347648318447f;   // 1/sqrt(128)

    const float qv = bfs2f(qC[(size_t)row*NKD + h*DH + d]);
    const unsigned* kb = kv + (size_t)b*NDV*NKD + h*DH + d;

    float m = -INFINITY, ssum = 0.f, acc = 0.f;
    for (int l0 = 0; l0 < NDV; l0 += 2) {
        int l = l0 + half;
        unsigned ur = kb[(size_t)l*NKD];
        float kr = bf2f(ur & 0xffffu);
        float vr = bf2f(ur >> 16);
        float partial = qv * kr;
        #pragma unroll
        for (int off = 16; off; off >>= 1) partial += __shfl_xor(partial, off);
        float s = partial * scale;
        float mn = fmaxf(m, s);
        float corr = __expf(m - mn);
        float p = __expf(s - mn);
        ssum = ssum * corr + p;
        acc  = acc  * corr + p * vr;
        m = mn;
    }
    float mo = __shfl_xor(m, 32);
    float M = fmaxf(m, mo);
    float corr = (m > -1e30f) ? __expf(m - M) : 0.f;
    ssum *= corr; acc *= corr;
    ssum += __shfl_xor(ssum, 32);
    acc  += __shfl_xor(acc, 32);
    if (half == 0) {
        float res = (ssum > 0.f) ? acc / ssum : 0.f;
        os[h*DH + d] = f2bf(qv + res);
    }
    __syncthreads();

    const int n = tid >> 1;
    const int ks = (tid & 1) * 64;
    float a = 0.f;
    const short* wrow = wo + (size_t)n*NKD + ks;
    #pragma unroll
    for (int kk = 0; kk < 64; kk += 8) {
        short8 o8 = *(short8*)&os[ks + kk];
        short8 w8 = *(const short8*)(wrow + kk);
        #pragma unroll
        for (int j = 0; j < 8; j++) a += bfs2f(o8[j]) * bfs2f(w8[j]);
    }
    a += __shfl_xor(a, 1);
    if ((tid & 1) == 0) {
        float val = a + bo[n];
        val = bfs2f(os[n]) + fmaxf(val, 0.f);
        C1[(size_t)row*NKD + n] = f2bf(val);
    }
}

// Final head with inline gathers of k_t, k_c (bf16 inputs)
__global__ __launch_bounds__(256)
void k_out(const short* __restrict__ U, const short* __restrict__ T1,
           const short* __restrict__ C1, const int* __restrict__ tind,
           const int* __restrict__ cind, const float* __restrict__ ow,
           const float* __restrict__ obp, float* __restrict__ out,
           int BL, int L)
{
    int row = blockIdx.x * 4 + (threadIdx.x >> 6);
    int lane = threadIdx.x & 63;
    if (row >= BL) return;
    int b = row / L;
    int ti = tind[row]; if (ti < 0) ti = 0;
    int ci = cind[row]; if (ci < 0) ci = 0;
    const short* u = U + (size_t)row*NKD;
    const short* a = T1 + ((size_t)(b*SS + ti))*NKD;
    const short* c = C1 + ((size_t)(b*NDV + ci))*NKD;
    float s = bfs2f(u[lane])*ow[lane]     + bfs2f(u[lane+64])*ow[lane+64]
            + bfs2f(a[lane])*ow[128+lane] + bfs2f(a[lane+64])*ow[192+lane]
            + bfs2f(c[lane])*ow[256+lane] + bfs2f(c[lane+64])*ow[320+lane];
    #pragma unroll
    for (int off = 32; off; off >>= 1) s += __shfl_down(s, off);
    if (lane == 0) out[row] = s + obp[0];
}

// ---------------------------------------------------------------------------
extern "C" void kernel_launch(void* const* d_in, const int* in_sizes, int n_in,
                              void* d_out, int out_size, void* d_ws, size_t ws_size,
                              hipStream_t stream)
{
    const float* cx     = (const float*)d_in[0];
    const float* value  = (const float*)d_in[1];
    const float* maskp  = (const float*)d_in[2];
    const float* tval   = (const float*)d_in[3];
    const float* tmaskp = (const float*)d_in[4];
    const float* w0     = (const float*)d_in[5];
    const float* b0     = (const float*)d_in[6];
    const float* edge_w = (const float*)d_in[7];
    const float* edge_b = (const float*)d_in[8];
    const float* chan_w = (const float*)d_in[9];
    const float* chan_b = (const float*)d_in[10];
    const float* time_w = (const float*)d_in[11];
    const float* time_b = (const float*)d_in[12];
    const float* ct_wq = (const float*)d_in[13];
    const float* ct_bq = (const float*)d_in[14];
    const float* ct_wk = (const float*)d_in[15];
    const float* ct_bk = (const float*)d_in[16];
    const float* ct_wv = (const float*)d_in[17];
    const float* ct_bv = (const float*)d_in[18];
    const float* ct_wo = (const float*)d_in[19];
    const float* ct_bo = (const float*)d_in[20];
    const float* tc_wq = (const float*)d_in[21];
    const float* tc_bq = (const float*)d_in[22];
    const float* tc_wk = (const float*)d_in[23];
    const float* tc_bk = (const float*)d_in[24];
    const float* tc_wv = (const float*)d_in[25];
    const float* tc_bv = (const float*)d_in[26];
    const float* tc_wo = (const float*)d_in[27];
    const float* tc_bo = (const float*)d_in[28];
    const float* ca_wq = (const float*)d_in[29];
    const float* ca_bq = (const float*)d_in[30];
    const float* ca_wk = (const float*)d_in[31];
    const float* ca_bk = (const float*)d_in[32];
    const float* ca_wv = (const float*)d_in[33];
    const float* ca_bv = (const float*)d_in[34];
    const float* ca_wo = (const float*)d_in[35];
    const float* ca_bo = (const float*)d_in[36];
    const float* en_w  = (const float*)d_in[37];
    const float* en_b  = (const float*)d_in[38];
    const float* out_w = (const float*)d_in[39];
    const float* out_b = (const float*)d_in[40];

    const int BL = out_size / 3;     // B * full_len
    const int L  = BL / NB;

    char* p = (char*)d_ws;
    auto alloc = [&](size_t n) { char* r = p; p += (n + 255) & ~(size_t)255; return r; };
    int*      tind   = (int*)  alloc((size_t)BL*4);
    int*      cind   = (int*)  alloc((size_t)BL*4);
    float*    mkb    = (float*)alloc((size_t)BL*4);
    float*    uval   = (float*)alloc((size_t)BL*4);
    float*    uind   = (float*)alloc((size_t)BL*4);
    int*      lo_t   = (int*)  alloc((size_t)NB*SS*4);
    int*      hi_t   = (int*)  alloc((size_t)NB*SS*4);
    int*      clo    = (int*)  alloc((size_t)NB*NDV*4);
    int*      chi    = (int*)  alloc((size_t)NB*NDV*4);
    int*      invp   = (int*)  alloc((size_t)BL*4);
    int*      chunkc = (int*)  alloc((size_t)NB*NCH*4);
    short*    waren  = (short*)alloc((size_t)W_TOTAL*2);
    short*    U    = (short*)alloc((size_t)BL*NKD*2);
    short*    Unew = (short*)alloc((size_t)BL*NKD*2);
    unsigned* KVct = (unsigned*)alloc((size_t)BL*NKD*4);
    unsigned* KVtc = (unsigned*)alloc((size_t)BL*NKD*4);
    unsigned* kvCa = (unsigned*)alloc((size_t)NB*NDV*NKD*4);
    short*    T1   = (short*)alloc((size_t)NB*SS*NKD*2);
    short*    T2b  = (short*)alloc((size_t)NB*SS*NKD*2);
    short*    qT   = (short*)alloc((size_t)NB*SS*NKD*2);
    short*    oT   = (short*)alloc((size_t)NB*SS*NKD*2);
    short*    C1   = (short*)alloc((size_t)NB*NDV*NKD*2);
    short*    qC   = (short*)alloc((size_t)NB*NDV*NKD*2);
    short*    oC   = (short*)alloc((size_t)NB*NDV*NKD*2);

    float* outMain = (float*)d_out;
    float* outTU = outMain + BL;
    float* outTM = outMain + 2*BL;

    // weight arena offsets (shorts)
    const size_t OCTQ=0, OCTK=49152, OCTV=147456, OCTO=245760;
    const size_t OTCQ=294912, OTCK=344064, OTCV=442368, OTCO=540672;
    const size_t OCAQ=589824, OCAK=638976, OCAV=688128, OCAO=737280, OEN=786432;

    // Pre-phases (3 dispatches — R14 measured-best structure)
    k_pre1<<<NB*NCH + 16 + 256 + 42 + W_TOTAL/256, 256, 0, stream>>>(
        maskp, chunkc, lo_t, hi_t, cx, time_w, time_b, T1, chan_w, chan_b, C1,
        ct_wq, ct_wk, ct_wv, ct_wo, tc_wq, tc_wk, tc_wv, tc_wo,
        ca_wq, ca_wk, ca_wv, ca_wo, en_w, waren);
    k_compactC<<<NB*NCH, 256, 0, stream>>>(cx, value, maskp, tval, tmaskp, w0, b0,
                                           chunkc, L, tind, cind, mkb, uval, uind,
                                           outTU, outTM);
    {
        const int gTr = (NB*L + 255)/256;
        const int gU  = (BL*16 + 255)/256;
        k_pre4<<<gTr + NB + gU, 256, 0, stream>>>(
            tind, lo_t, hi_t, L, gTr, cind, invp, clo, chi,
            uval, uind, mkb, edge_w, edge_b, U, BL);
    }

    const int gBL  = (BL + 127)/128;
    const int gKV  = (BL + 63)/64;       // M-tile 64 (measured best)
    const int gC   = (NB*NDV + 127)/128;
    const int gT   = (NB*SS + 127)/128;
    const int gCa  = (NB*NDV + 63)/64;
    const int aC2  = NB*NDV*NHD*2/4;     // SPLIT=2
    const int aTC  = NB*SS*NHD/4;        // SPLIT=1

    for (int i = 0; i < NLAY; i++) {
        const size_t bOff = (size_t)i*NKD;
        const short* wq_ct = waren + OCTQ + (size_t)i*128*128;
        const short* wk_ct = waren + OCTK + (size_t)i*256*128;
        const short* wv_ct = waren + OCTV + (size_t)i*256*128;
        const short* wo_ct = waren + OCTO + (size_t)i*128*128;
        const short* wq_tc = waren + OTCQ + (size_t)i*128*128;
        const short* wk_tc = waren + OTCK + (size_t)i*256*128;
        const short* wv_tc = waren + OTCV + (size_t)i*256*128;
        const short* wo_tc = waren + OTCO + (size_t)i*128*128;
        const short* wq_ca = waren + OCAQ + (size_t)i*128*128;
        const short* wk_ca = waren + OCAK + (size_t)i*128*128;
        const short* wv_ca = waren + OCAV + (size_t)i*128*128;
        const short* wo_ca = waren + OCAO + (size_t)i*128*128;
        const short* w_en  = waren + OEN  + (size_t)i*384*128;

        // P1: q/kv projections from (T1, C1, U)
        k_phase1<<<gKV + gC + gKV + gT, 256, 0, stream>>>(
            gKV, gC, gKV,
            T1, tind, U,
            wk_ct, ct_bk + bOff, wv_ct, ct_bv + bOff, KVct, invp,
            C1, wq_ct, ct_bq + bOff, qC,
            cind, wk_tc, tc_bk + bOff, wv_tc, tc_bv + bOff, KVtc,
            wq_tc, tc_bq + bOff, qT, BL, L);
        // P2: both segmented attentions
        k_phase2<<<aC2 + aTC, 256, 0, stream>>>(
            aC2, qC, KVct, oC, clo, chi, L, qT, KVtc, oT, lo_t, hi_t);
        // P3: fused ct-o-proj+ca-kvq | o-tc | en
        k_phase3<<<gCa + gT + gBL, 256, 0, stream>>>(
            gCa, gT,
            oC, wo_ct, ct_bo + bOff,
            wq_ca, ca_bq + bOff, wk_ca, ca_bk + bOff, wv_ca, ca_bv + bOff,
            qC, kvCa,
            oT, wo_tc, tc_bo + bOff, T2b,
            U, T1, tind, C1, cind, w_en, en_b + bOff, Unew, mkb, BL, L);
        // P4: fused ca attention + o-proj (672 blocks — stays parallel)
        k_ca_fused<<<NB*NDV, 256, 0, stream>>>(qC, kvCa, wo_ca, ca_bo + bOff, C1);

        short* t = U;  U = Unew; Unew = t;
        t = T1; T1 = T2b; T2b = t;
    }

    k_out<<<(BL + 3)/4, 256, 0, stream>>>(U, T1, C1, tind, cind,
                                          out_w, out_b, outMain, BL, L);
}